// Round 1
// baseline (896.493 us; speedup 1.0000x reference)
//
#include <hip/hip_runtime.h>

#define HS 1024
#define VS 32000
#define BS 64
#define SS 2048
#define NCH 32
#define SCH (SS/NCH)   // 64 seq positions per chunk

__device__ __forceinline__ float sigmf(float x) { return 1.0f / (1.0f + __expf(-x)); }

// ---------------------------------------------------------------------------
// 1. Embedding gather + transpose of x and h into [feature][batch] layout
// ---------------------------------------------------------------------------
__global__ __launch_bounds__(256) void k_gather(const int* __restrict__ idx,
    const float* __restrict__ emb, const float* __restrict__ hid,
    float* __restrict__ xt, float* __restrict__ ht) {
  int tid = blockIdx.x * 256 + threadIdx.x;   // H*B = 65536 threads
  int b = tid & 63, k = tid >> 6;
  xt[k * BS + b] = emb[(size_t)idx[b] * HS + k];
  ht[k * BS + b] = hid[b * HS + k];
}

// ---------------------------------------------------------------------------
// 2. GRU gates: gxt = (x @ w_ih^T + b_ih)^T, ght = (h @ w_hh^T + b_hh)^T
//    lane = batch; each wave owns 8 output rows (wave-uniform weight rows)
// ---------------------------------------------------------------------------
__global__ __launch_bounds__(256) void k_gates(const float* __restrict__ xt,
    const float* __restrict__ ht,
    const float* __restrict__ w_ih, const float* __restrict__ w_hh,
    const float* __restrict__ b_ih, const float* __restrict__ b_hh,
    float* __restrict__ gxt, float* __restrict__ ght) {
  int lane = threadIdx.x & 63;
  int wv = __builtin_amdgcn_readfirstlane(threadIdx.x >> 6);
  int j0 = (blockIdx.x * 4 + wv) * 8;   // 96 blocks * 4 waves * 8 = 3072 rows
  const float *src, *w, *bias;
  float* dst;
  if (blockIdx.y == 0) { src = xt; w = w_ih; bias = b_ih; dst = gxt; }
  else                 { src = ht; w = w_hh; bias = b_hh; dst = ght; }
  float acc[8];
#pragma unroll
  for (int jj = 0; jj < 8; jj++) acc[jj] = bias[j0 + jj];
  for (int k = 0; k < HS; k += 4) {
    float x0 = src[(k + 0) * BS + lane];
    float x1 = src[(k + 1) * BS + lane];
    float x2 = src[(k + 2) * BS + lane];
    float x3 = src[(k + 3) * BS + lane];
#pragma unroll
    for (int jj = 0; jj < 8; jj++) {
      const float* wp = w + (size_t)(j0 + jj) * HS + k;
      acc[jj] = fmaf(wp[0], x0, acc[jj]);
      acc[jj] = fmaf(wp[1], x1, acc[jj]);
      acc[jj] = fmaf(wp[2], x2, acc[jj]);
      acc[jj] = fmaf(wp[3], x3, acc[jj]);
    }
  }
#pragma unroll
  for (int jj = 0; jj < 8; jj++) dst[(j0 + jj) * BS + lane] = acc[jj];
}

// ---------------------------------------------------------------------------
// 3. GRU nonlinearity -> h_new (transposed ws copy + [1,B,H] output)
// ---------------------------------------------------------------------------
__global__ __launch_bounds__(256) void k_hnew(const float* __restrict__ gxt,
    const float* __restrict__ ght, const float* __restrict__ ht,
    float* __restrict__ hnt, float* __restrict__ out_h) {
  int tid = blockIdx.x * 256 + threadIdx.x;   // 65536
  int b = tid & 63, i = tid >> 6;
  float r = sigmf(gxt[i * BS + b] + ght[i * BS + b]);
  float z = sigmf(gxt[(HS + i) * BS + b] + ght[(HS + i) * BS + b]);
  float n = tanhf(gxt[(2 * HS + i) * BS + b] + r * ght[(2 * HS + i) * BS + b]);
  float hv = ht[i * BS + b];
  float hn = (1.0f - z) * n + z * hv;
  hnt[i * BS + b] = hn;
  out_h[b * HS + i] = hn;
}

// ---------------------------------------------------------------------------
// 4. q = h_new @ attn_w   (qt transposed [h][b]).  attn_b is dropped: it adds
//    a per-b constant to all scores -> cancels in softmax; scores not output.
// ---------------------------------------------------------------------------
__global__ __launch_bounds__(256) void k_q(const float* __restrict__ hnt,
    const float* __restrict__ aw, float* __restrict__ qt) {
  int lane = threadIdx.x & 63;
  int wv = __builtin_amdgcn_readfirstlane(threadIdx.x >> 6);
  int p0 = (blockIdx.x * 4 + wv) * 8;   // 32 blocks
  float acc[8] = {0.f, 0.f, 0.f, 0.f, 0.f, 0.f, 0.f, 0.f};
  for (int g = 0; g < HS; g += 2) {
    float h0 = hnt[g * BS + lane];
    float h1 = hnt[(g + 1) * BS + lane];
    const float* a0 = aw + (size_t)g * HS + p0;
    const float* a1 = aw + (size_t)(g + 1) * HS + p0;
#pragma unroll
    for (int jj = 0; jj < 8; jj++)
      acc[jj] = fmaf(a0[jj], h0, fmaf(a1[jj], h1, acc[jj]));
  }
#pragma unroll
  for (int jj = 0; jj < 8; jj++) qt[(p0 + jj) * BS + lane] = acc[jj];
}

// ---------------------------------------------------------------------------
// 5. Fused scores + online softmax + context over a chunk of S.
//    One block per (b, chunk); single pass over encoder_outputs (512 MB).
// ---------------------------------------------------------------------------
__global__ __launch_bounds__(256) void k_attn(const float* __restrict__ enc,
    const float* __restrict__ qt, float* __restrict__ scores,
    float* __restrict__ mch, float* __restrict__ lch, float* __restrict__ ctxp) {
  int b = blockIdx.x & 63;
  int ch = blockIdx.x >> 6;
  int t = threadIdx.x;
  int h0 = t * 4;
  float q0 = qt[(h0 + 0) * BS + b];
  float q1 = qt[(h0 + 1) * BS + b];
  float q2 = qt[(h0 + 2) * BS + b];
  float q3 = qt[(h0 + 3) * BS + b];
  __shared__ float red[4];
  float m = -1e30f, l = 0.f;
  float a0 = 0.f, a1 = 0.f, a2 = 0.f, a3 = 0.f;
  int s0 = ch * SCH;
  float4 e = *(const float4*)(enc + ((size_t)s0 * BS + b) * HS + h0);
  for (int si = 0; si < SCH; si++) {
    float4 ec = e;
    if (si + 1 < SCH)   // prefetch next position
      e = *(const float4*)(enc + ((size_t)(s0 + si + 1) * BS + b) * HS + h0);
    float p = fmaf(ec.x, q0, fmaf(ec.y, q1, fmaf(ec.z, q2, ec.w * q3)));
#pragma unroll
    for (int off = 32; off; off >>= 1) p += __shfl_xor(p, off, 64);
    if ((t & 63) == 0) red[t >> 6] = p;
    __syncthreads();
    float score = red[0] + red[1] + red[2] + red[3];
    __syncthreads();
    if (t == 0) scores[b * SS + s0 + si] = score;
    float mn = fmaxf(m, score);
    float sc = __expf(m - mn);       // first iter: exp(-huge) = 0
    float pr = __expf(score - mn);
    l = fmaf(l, sc, pr);
    a0 = fmaf(a0, sc, pr * ec.x);
    a1 = fmaf(a1, sc, pr * ec.y);
    a2 = fmaf(a2, sc, pr * ec.z);
    a3 = fmaf(a3, sc, pr * ec.w);
    m = mn;
  }
  if (t == 0) { mch[b * NCH + ch] = m; lch[b * NCH + ch] = l; }
  float4 o = {a0, a1, a2, a3};
  *(float4*)(ctxp + ((size_t)(b * NCH + ch)) * HS + h0) = o;
}

// ---------------------------------------------------------------------------
// 6. Combine chunk partials -> context (transposed), softmax weights output
// ---------------------------------------------------------------------------
__global__ __launch_bounds__(256) void k_combine(const float* __restrict__ mch,
    const float* __restrict__ lch, const float* __restrict__ ctxp,
    const float* __restrict__ scores, float* __restrict__ ctxt,
    float* __restrict__ wout) {
  int b = blockIdx.x;
  int t = threadIdx.x;
  __shared__ float sm[NCH], sl[NCH], ssc[NCH];
  if (t < NCH) { sm[t] = mch[b * NCH + t]; sl[t] = lch[b * NCH + t]; }
  __syncthreads();
  float mstar = -1e30f;
  for (int c = 0; c < NCH; c++) mstar = fmaxf(mstar, sm[c]);
  if (t < NCH) ssc[t] = __expf(sm[t] - mstar);
  __syncthreads();
  float L = 0.f;
  for (int c = 0; c < NCH; c++) L = fmaf(sl[c], ssc[c], L);
  float invL = 1.0f / L;
  int h0 = t * 4;
  float a0 = 0, a1 = 0, a2 = 0, a3 = 0;
  for (int c = 0; c < NCH; c++) {
    float4 v = *(const float4*)(ctxp + ((size_t)(b * NCH + c)) * HS + h0);
    float s = ssc[c];
    a0 = fmaf(v.x, s, a0); a1 = fmaf(v.y, s, a1);
    a2 = fmaf(v.z, s, a2); a3 = fmaf(v.w, s, a3);
  }
  ctxt[(h0 + 0) * BS + b] = a0 * invL;
  ctxt[(h0 + 1) * BS + b] = a1 * invL;
  ctxt[(h0 + 2) * BS + b] = a2 * invL;
  ctxt[(h0 + 3) * BS + b] = a3 * invL;
  for (int s = t; s < SS; s += 256)
    wout[b * SS + s] = __expf(scores[b * SS + s] - mstar) * invL;
}

// ---------------------------------------------------------------------------
// 7. concat_output = tanh([h_new, context] @ concat_w^T + concat_b)
// ---------------------------------------------------------------------------
__global__ __launch_bounds__(256) void k_concat(const float* __restrict__ hnt,
    const float* __restrict__ ctxt, const float* __restrict__ cw,
    const float* __restrict__ cb, float* __restrict__ cot) {
  int lane = threadIdx.x & 63;
  int wv = __builtin_amdgcn_readfirstlane(threadIdx.x >> 6);
  int i0 = (blockIdx.x * 4 + wv) * 8;   // 32 blocks
  float acc[8];
#pragma unroll
  for (int jj = 0; jj < 8; jj++) acc[jj] = cb[i0 + jj];
  for (int k = 0; k < HS; k += 2) {
    float h0v = hnt[k * BS + lane], h1v = hnt[(k + 1) * BS + lane];
    float c0v = ctxt[k * BS + lane], c1v = ctxt[(k + 1) * BS + lane];
#pragma unroll
    for (int jj = 0; jj < 8; jj++) {
      const float* wp = cw + (size_t)(i0 + jj) * (2 * HS);
      acc[jj] = fmaf(wp[k], h0v, acc[jj]);
      acc[jj] = fmaf(wp[k + 1], h1v, acc[jj]);
      acc[jj] = fmaf(wp[HS + k], c0v, acc[jj]);
      acc[jj] = fmaf(wp[HS + k + 1], c1v, acc[jj]);
    }
  }
#pragma unroll
  for (int jj = 0; jj < 8; jj++) cot[(i0 + jj) * BS + lane] = tanhf(acc[jj]);
}

// ---------------------------------------------------------------------------
// 8. output = concat_output @ out_w^T + out_b   (B x V)
// ---------------------------------------------------------------------------
__global__ __launch_bounds__(256) void k_out(const float* __restrict__ cot,
    const float* __restrict__ ow, const float* __restrict__ ob,
    float* __restrict__ out0) {
  int lane = threadIdx.x & 63;
  int wv = __builtin_amdgcn_readfirstlane(threadIdx.x >> 6);
  int v0 = (blockIdx.x * 4 + wv) * 8;   // 1000 blocks: 32000 rows
  float acc[8];
#pragma unroll
  for (int jj = 0; jj < 8; jj++) acc[jj] = ob[v0 + jj];
  for (int k = 0; k < HS; k += 4) {
    float c0 = cot[(k + 0) * BS + lane];
    float c1 = cot[(k + 1) * BS + lane];
    float c2 = cot[(k + 2) * BS + lane];
    float c3 = cot[(k + 3) * BS + lane];
#pragma unroll
    for (int jj = 0; jj < 8; jj++) {
      const float* wp = ow + (size_t)(v0 + jj) * HS + k;
      acc[jj] = fmaf(wp[0], c0, acc[jj]);
      acc[jj] = fmaf(wp[1], c1, acc[jj]);
      acc[jj] = fmaf(wp[2], c2, acc[jj]);
      acc[jj] = fmaf(wp[3], c3, acc[jj]);
    }
  }
#pragma unroll
  for (int jj = 0; jj < 8; jj++) out0[(size_t)lane * VS + v0 + jj] = acc[jj];
}

// ---------------------------------------------------------------------------
extern "C" void kernel_launch(void* const* d_in, const int* in_sizes, int n_in,
                              void* d_out, int out_size, void* d_ws, size_t ws_size,
                              hipStream_t stream) {
  const int*   idx  = (const int*)d_in[0];
  const float* hid  = (const float*)d_in[1];
  const float* enc  = (const float*)d_in[2];
  const float* emb  = (const float*)d_in[3];
  const float* w_ih = (const float*)d_in[4];
  const float* w_hh = (const float*)d_in[5];
  const float* b_ih = (const float*)d_in[6];
  const float* b_hh = (const float*)d_in[7];
  const float* aw   = (const float*)d_in[8];
  // d_in[9] = attn_b: adds a per-b constant to every score -> cancels in
  // softmax; raw scores are not an output. Safe to ignore for ANY attn_b.
  const float* cw   = (const float*)d_in[10];
  const float* cb   = (const float*)d_in[11];
  const float* ow   = (const float*)d_in[12];
  const float* ob   = (const float*)d_in[13];

  float* out0  = (float*)d_out;                   // [B, V]
  float* out_h = out0 + (size_t)BS * VS;          // [1, B, H]
  float* out_w = out_h + (size_t)BS * HS;         // [B, 1, S]

  // workspace layout (floats); total ~3.15M floats = 12.6 MB
  float* ws   = (float*)d_ws;
  float* xt   = ws;                               // [H][B]
  float* ht   = xt  + (size_t)HS * BS;            // [H][B]
  float* gxt  = ht  + (size_t)HS * BS;            // [3H][B]
  float* ght  = gxt + (size_t)3 * HS * BS;        // [3H][B]
  float* hnt  = ght + (size_t)3 * HS * BS;        // [H][B]
  float* qt   = hnt + (size_t)HS * BS;            // [H][B]
  float* scr  = qt  + (size_t)HS * BS;            // [B][S]
  float* mch  = scr + (size_t)BS * SS;            // [B][NCH]
  float* lch  = mch + (size_t)BS * NCH;           // [B][NCH]
  float* ctxp = lch + (size_t)BS * NCH;           // [B*NCH][H]
  float* ctxt = ctxp + (size_t)BS * NCH * HS;     // [H][B]
  float* cot  = ctxt + (size_t)HS * BS;           // [H][B]

  k_gather <<<dim3(HS * BS / 256), dim3(256), 0, stream>>>(idx, emb, hid, xt, ht);
  k_gates  <<<dim3(96, 2), dim3(256), 0, stream>>>(xt, ht, w_ih, w_hh, b_ih, b_hh, gxt, ght);
  k_hnew   <<<dim3(HS * BS / 256), dim3(256), 0, stream>>>(gxt, ght, ht, hnt, out_h);
  k_q      <<<dim3(HS / 32), dim3(256), 0, stream>>>(hnt, aw, qt);
  k_attn   <<<dim3(BS * NCH), dim3(256), 0, stream>>>(enc, qt, scr, mch, lch, ctxp);
  k_combine<<<dim3(BS), dim3(256), 0, stream>>>(mch, lch, ctxp, scr, ctxt, out_w);
  k_concat <<<dim3(HS / 32), dim3(256), 0, stream>>>(hnt, ctxt, cw, cb, cot);
  k_out    <<<dim3(VS / 32), dim3(256), 0, stream>>>(cot, ow, ob, out0);
}

// Round 2
// 813.425 us; speedup vs baseline: 1.1021x; 1.1021x over previous
//
#include <hip/hip_runtime.h>

#define HS 1024
#define VS 32000
#define BS 64
#define SS 2048
#define NCH 64
#define SCH (SS/NCH)   // 32 seq positions per wave-chunk

__device__ __forceinline__ float sigmf(float x) { return 1.0f / (1.0f + __expf(-x)); }

// ---------------------------------------------------------------------------
// 1. Embedding gather + transpose of x and h into [feature][batch] layout.
//    k fastest -> coalesced row reads; scattered 4B writes are only ~8 MB.
// ---------------------------------------------------------------------------
__global__ __launch_bounds__(256) void k_gather(const int* __restrict__ idx,
    const float* __restrict__ emb, const float* __restrict__ hid,
    float* __restrict__ xt, float* __restrict__ ht) {
  int tid = blockIdx.x * 256 + threadIdx.x;   // H*B = 65536 threads
  int b = tid >> 10, k = tid & 1023;
  xt[k * BS + b] = emb[(size_t)idx[b] * HS + k];
  ht[k * BS + b] = hid[(size_t)b * HS + k];
}

// ---------------------------------------------------------------------------
// 2. GRU gates, split-K: block = 8 rows, 4 waves each own a 256-wide K-slice,
//    LDS combine. grid (384, 2). lane = batch (coalesced activations),
//    weight rows wave-uniform -> scalar loads.
// ---------------------------------------------------------------------------
__global__ __launch_bounds__(256) void k_gates(const float* __restrict__ xt,
    const float* __restrict__ ht,
    const float* __restrict__ w_ih, const float* __restrict__ w_hh,
    const float* __restrict__ b_ih, const float* __restrict__ b_hh,
    float* __restrict__ gxt, float* __restrict__ ght) {
  int lane = threadIdx.x & 63;
  int wv = __builtin_amdgcn_readfirstlane(threadIdx.x >> 6);
  int j0 = blockIdx.x * 8;
  const float *src, *w, *bias;
  float* dst;
  if (blockIdx.y == 0) { src = xt; w = w_ih; bias = b_ih; dst = gxt; }
  else                 { src = ht; w = w_hh; bias = b_hh; dst = ght; }
  int g0 = wv * 256;
  float acc[8] = {0.f, 0.f, 0.f, 0.f, 0.f, 0.f, 0.f, 0.f};
  for (int g = g0; g < g0 + 256; g += 2) {
    float x0 = src[g * BS + lane];
    float x1 = src[(g + 1) * BS + lane];
#pragma unroll
    for (int jj = 0; jj < 8; jj++) {
      const float* wp = w + (size_t)(j0 + jj) * HS + g;
      acc[jj] = fmaf(wp[0], x0, fmaf(wp[1], x1, acc[jj]));
    }
  }
  __shared__ float red[4][8][64];
#pragma unroll
  for (int jj = 0; jj < 8; jj++) red[wv][jj][lane] = acc[jj];
  __syncthreads();
#pragma unroll
  for (int u = 0; u < 2; u++) {
    int jj = wv * 2 + u;
    float v = red[0][jj][lane] + red[1][jj][lane] + red[2][jj][lane] +
              red[3][jj][lane] + bias[j0 + jj];
    dst[(size_t)(j0 + jj) * BS + lane] = v;
  }
}

// ---------------------------------------------------------------------------
// 3. GRU nonlinearity -> h_new (transposed ws copy + [1,B,H] output)
// ---------------------------------------------------------------------------
__global__ __launch_bounds__(256) void k_hnew(const float* __restrict__ gxt,
    const float* __restrict__ ght, const float* __restrict__ ht,
    float* __restrict__ hnt, float* __restrict__ out_h) {
  int tid = blockIdx.x * 256 + threadIdx.x;   // 65536
  int b = tid & 63, i = tid >> 6;
  float r = sigmf(gxt[i * BS + b] + ght[i * BS + b]);
  float z = sigmf(gxt[(HS + i) * BS + b] + ght[(HS + i) * BS + b]);
  float n = tanhf(gxt[(2 * HS + i) * BS + b] + r * ght[(2 * HS + i) * BS + b]);
  float hv = ht[i * BS + b];
  float hn = (1.0f - z) * n + z * hv;
  hnt[i * BS + b] = hn;
  out_h[b * HS + i] = hn;
}

// ---------------------------------------------------------------------------
// 4. q = h_new @ attn_w, row layout qrow[b][p]. Split-K: 128 blocks of
//    8 p-values, 4 waves x 256-K-slice, LDS combine. attn_b dropped: adds a
//    per-b constant to every score -> cancels in softmax; scores not output.
// ---------------------------------------------------------------------------
__global__ __launch_bounds__(256) void k_q(const float* __restrict__ hnt,
    const float* __restrict__ aw, float* __restrict__ qrow) {
  int lane = threadIdx.x & 63;
  int wv = __builtin_amdgcn_readfirstlane(threadIdx.x >> 6);
  int p0 = blockIdx.x * 8;
  int g0 = wv * 256;
  float acc[8] = {0.f, 0.f, 0.f, 0.f, 0.f, 0.f, 0.f, 0.f};
  for (int g = g0; g < g0 + 256; g += 2) {
    float h0v = hnt[g * BS + lane];
    float h1v = hnt[(g + 1) * BS + lane];
    const float* a0p = aw + (size_t)g * HS + p0;
    const float* a1p = a0p + HS;
#pragma unroll
    for (int jj = 0; jj < 8; jj++)
      acc[jj] = fmaf(a0p[jj], h0v, fmaf(a1p[jj], h1v, acc[jj]));
  }
  __shared__ float red[4][8][64];
#pragma unroll
  for (int jj = 0; jj < 8; jj++) red[wv][jj][lane] = acc[jj];
  __syncthreads();
  float2 qv;
  {
    int jj = wv * 2;
    qv.x = red[0][jj][lane] + red[1][jj][lane] + red[2][jj][lane] + red[3][jj][lane];
    jj++;
    qv.y = red[0][jj][lane] + red[1][jj][lane] + red[2][jj][lane] + red[3][jj][lane];
  }
  *(float2*)(qrow + (size_t)lane * HS + p0 + wv * 2) = qv;
}

// ---------------------------------------------------------------------------
// 5. Fused scores + online softmax + context: ONE WAVE per (b, chunk).
//    No barriers; 64-lane XOR butterfly broadcasts the score to all lanes;
//    each lane owns 16 h-positions (j*256 + lane*4) -> fully coalesced.
// ---------------------------------------------------------------------------
__global__ __launch_bounds__(256) void k_attn(const float* __restrict__ enc,
    const float* __restrict__ qrow, float* __restrict__ scores,
    float* __restrict__ mch, float* __restrict__ lch, float* __restrict__ ctxp) {
  int lane = threadIdx.x & 63;
  int w = blockIdx.x * 4 + (threadIdx.x >> 6);   // 4096 waves
  int b = w & 63;
  int ch = w >> 6;                               // 0..63
  const float* qb = qrow + (size_t)b * HS;
  float4 q0 = *(const float4*)(qb + 0   + lane * 4);
  float4 q1 = *(const float4*)(qb + 256 + lane * 4);
  float4 q2 = *(const float4*)(qb + 512 + lane * 4);
  float4 q3 = *(const float4*)(qb + 768 + lane * 4);
  int s0 = ch * SCH;
  const float* ep = enc + ((size_t)s0 * BS + b) * HS;
  float4 e0 = *(const float4*)(ep + 0   + lane * 4);
  float4 e1 = *(const float4*)(ep + 256 + lane * 4);
  float4 e2 = *(const float4*)(ep + 512 + lane * 4);
  float4 e3 = *(const float4*)(ep + 768 + lane * 4);
  float m = -1e30f, l = 0.f;
  float4 a0 = {0, 0, 0, 0}, a1 = {0, 0, 0, 0}, a2 = {0, 0, 0, 0}, a3 = {0, 0, 0, 0};
  for (int si = 0; si < SCH; si++) {
    float4 c0 = e0, c1 = e1, c2 = e2, c3 = e3;
    if (si + 1 < SCH) {
      const float* np = ep + (size_t)BS * HS;
      e0 = *(const float4*)(np + 0   + lane * 4);
      e1 = *(const float4*)(np + 256 + lane * 4);
      e2 = *(const float4*)(np + 512 + lane * 4);
      e3 = *(const float4*)(np + 768 + lane * 4);
    }
    ep += (size_t)BS * HS;
    float d0 = fmaf(c0.x, q0.x, fmaf(c0.y, q0.y, fmaf(c0.z, q0.z, c0.w * q0.w)));
    float d1 = fmaf(c1.x, q1.x, fmaf(c1.y, q1.y, fmaf(c1.z, q1.z, c1.w * q1.w)));
    float d2 = fmaf(c2.x, q2.x, fmaf(c2.y, q2.y, fmaf(c2.z, q2.z, c2.w * q2.w)));
    float d3 = fmaf(c3.x, q3.x, fmaf(c3.y, q3.y, fmaf(c3.z, q3.z, c3.w * q3.w)));
    float p = (d0 + d1) + (d2 + d3);
#pragma unroll
    for (int off = 32; off; off >>= 1) p += __shfl_xor(p, off, 64);
    if (lane == 0) scores[(size_t)b * SS + s0 + si] = p;
    float mn = fmaxf(m, p);
    float sc = __expf(m - mn);   // first iter: exp(-huge) = 0
    float pr = __expf(p - mn);
    l = fmaf(l, sc, pr);
    a0.x = fmaf(a0.x, sc, pr * c0.x); a0.y = fmaf(a0.y, sc, pr * c0.y);
    a0.z = fmaf(a0.z, sc, pr * c0.z); a0.w = fmaf(a0.w, sc, pr * c0.w);
    a1.x = fmaf(a1.x, sc, pr * c1.x); a1.y = fmaf(a1.y, sc, pr * c1.y);
    a1.z = fmaf(a1.z, sc, pr * c1.z); a1.w = fmaf(a1.w, sc, pr * c1.w);
    a2.x = fmaf(a2.x, sc, pr * c2.x); a2.y = fmaf(a2.y, sc, pr * c2.y);
    a2.z = fmaf(a2.z, sc, pr * c2.z); a2.w = fmaf(a2.w, sc, pr * c2.w);
    a3.x = fmaf(a3.x, sc, pr * c3.x); a3.y = fmaf(a3.y, sc, pr * c3.y);
    a3.z = fmaf(a3.z, sc, pr * c3.z); a3.w = fmaf(a3.w, sc, pr * c3.w);
    m = mn;
  }
  if (lane == 0) { mch[b * NCH + ch] = m; lch[b * NCH + ch] = l; }
  float* cp = ctxp + ((size_t)(b * NCH + ch)) * HS;
  *(float4*)(cp + 0   + lane * 4) = a0;
  *(float4*)(cp + 256 + lane * 4) = a1;
  *(float4*)(cp + 512 + lane * 4) = a2;
  *(float4*)(cp + 768 + lane * 4) = a3;
}

// ---------------------------------------------------------------------------
// 6. Combine chunk partials -> context (transposed) + softmax weights output.
//    grid (64, 4): blockIdx.y picks a 256-wide h-slice.
// ---------------------------------------------------------------------------
__global__ __launch_bounds__(256) void k_combine(const float* __restrict__ mch,
    const float* __restrict__ lch, const float* __restrict__ ctxp,
    const float* __restrict__ scores, float* __restrict__ ctxt,
    float* __restrict__ wout) {
  int b = blockIdx.x;
  int t = threadIdx.x;
  __shared__ float sm[NCH], sl[NCH], ssc[NCH];
  if (t < NCH) { sm[t] = mch[b * NCH + t]; sl[t] = lch[b * NCH + t]; }
  __syncthreads();
  float mstar = -1e30f;
  for (int c = 0; c < NCH; c++) mstar = fmaxf(mstar, sm[c]);
  if (t < NCH) ssc[t] = __expf(sm[t] - mstar);
  __syncthreads();
  float L = 0.f;
  for (int c = 0; c < NCH; c++) L = fmaf(sl[c], ssc[c], L);
  float invL = 1.0f / L;
  int h = blockIdx.y * 256 + t;
  float acc = 0.f;
  for (int c = 0; c < NCH; c++)
    acc = fmaf(ctxp[((size_t)(b * NCH + c)) * HS + h], ssc[c], acc);
  ctxt[h * BS + b] = acc * invL;
  if (blockIdx.y == 0)
    for (int s = t; s < SS; s += 256)
      wout[(size_t)b * SS + s] = __expf(scores[(size_t)b * SS + s] - mstar) * invL;
}

// ---------------------------------------------------------------------------
// 7. concat_output = tanh([h_new, context] @ concat_w^T + concat_b)
//    Split-K: 128 blocks of 8 rows; wave wv owns a 512-wide K-slice
//    (waves 0-1: h_new half, waves 2-3: context half).
// ---------------------------------------------------------------------------
__global__ __launch_bounds__(256) void k_concat(const float* __restrict__ hnt,
    const float* __restrict__ ctxt, const float* __restrict__ cw,
    const float* __restrict__ cb, float* __restrict__ cot) {
  int lane = threadIdx.x & 63;
  int wv = __builtin_amdgcn_readfirstlane(threadIdx.x >> 6);
  int i0 = blockIdx.x * 8;
  const float* src;
  int kbase;
  if (wv < 2) { src = hnt + (size_t)wv * 512 * BS; kbase = wv * 512; }
  else        { src = ctxt + (size_t)(wv - 2) * 512 * BS; kbase = HS + (wv - 2) * 512; }
  float acc[8] = {0.f, 0.f, 0.f, 0.f, 0.f, 0.f, 0.f, 0.f};
  for (int g = 0; g < 512; g += 2) {
    float x0 = src[g * BS + lane];
    float x1 = src[(g + 1) * BS + lane];
#pragma unroll
    for (int jj = 0; jj < 8; jj++) {
      const float* wp = cw + (size_t)(i0 + jj) * (2 * HS) + kbase + g;
      acc[jj] = fmaf(wp[0], x0, fmaf(wp[1], x1, acc[jj]));
    }
  }
  __shared__ float red[4][8][64];
#pragma unroll
  for (int jj = 0; jj < 8; jj++) red[wv][jj][lane] = acc[jj];
  __syncthreads();
#pragma unroll
  for (int u = 0; u < 2; u++) {
    int jj = wv * 2 + u;
    float v = red[0][jj][lane] + red[1][jj][lane] + red[2][jj][lane] +
              red[3][jj][lane] + cb[i0 + jj];
    cot[(size_t)(i0 + jj) * BS + lane] = tanhf(v);
  }
}

// ---------------------------------------------------------------------------
// 8. output = concat_output @ out_w^T + out_b. Split-K: 2000 blocks of
//    16 vocab rows, 4 waves x 256-K-slice, LDS combine, float4 store.
// ---------------------------------------------------------------------------
__global__ __launch_bounds__(256) void k_out(const float* __restrict__ cot,
    const float* __restrict__ ow, const float* __restrict__ ob,
    float* __restrict__ out0) {
  int lane = threadIdx.x & 63;
  int wv = __builtin_amdgcn_readfirstlane(threadIdx.x >> 6);
  int v0 = blockIdx.x * 16;
  int g0 = wv * 256;
  float acc[16];
#pragma unroll
  for (int jj = 0; jj < 16; jj++) acc[jj] = 0.f;
  for (int g = g0; g < g0 + 256; g += 2) {
    float c0 = cot[g * BS + lane];
    float c1 = cot[(g + 1) * BS + lane];
#pragma unroll
    for (int jj = 0; jj < 16; jj++) {
      const float* wp = ow + (size_t)(v0 + jj) * HS + g;
      acc[jj] = fmaf(wp[0], c0, fmaf(wp[1], c1, acc[jj]));
    }
  }
  __shared__ float red[4][16][64];   // 16 KB
#pragma unroll
  for (int jj = 0; jj < 16; jj++) red[wv][jj][lane] = acc[jj];
  __syncthreads();
  float4 o;
  float* op = &o.x;
#pragma unroll
  for (int u = 0; u < 4; u++) {
    int jj = wv * 4 + u;
    op[u] = red[0][jj][lane] + red[1][jj][lane] + red[2][jj][lane] +
            red[3][jj][lane] + ob[v0 + jj];
  }
  *(float4*)(out0 + (size_t)lane * VS + v0 + wv * 4) = o;
}

// ---------------------------------------------------------------------------
extern "C" void kernel_launch(void* const* d_in, const int* in_sizes, int n_in,
                              void* d_out, int out_size, void* d_ws, size_t ws_size,
                              hipStream_t stream) {
  const int*   idx  = (const int*)d_in[0];
  const float* hid  = (const float*)d_in[1];
  const float* enc  = (const float*)d_in[2];
  const float* emb  = (const float*)d_in[3];
  const float* w_ih = (const float*)d_in[4];
  const float* w_hh = (const float*)d_in[5];
  const float* b_ih = (const float*)d_in[6];
  const float* b_hh = (const float*)d_in[7];
  const float* aw   = (const float*)d_in[8];
  // d_in[9] = attn_b: per-b constant on every score -> cancels in softmax.
  const float* cw   = (const float*)d_in[10];
  const float* cb   = (const float*)d_in[11];
  const float* ow   = (const float*)d_in[12];
  const float* ob   = (const float*)d_in[13];

  float* out0  = (float*)d_out;                   // [B, V]
  float* out_h = out0 + (size_t)BS * VS;          // [1, B, H]
  float* out_w = out_h + (size_t)BS * HS;         // [B, 1, S]

  // workspace layout (floats); total ~5.1M floats = 20.5 MB
  float* ws   = (float*)d_ws;
  float* xt   = ws;                               // [H][B]
  float* ht   = xt  + (size_t)HS * BS;            // [H][B]
  float* gxt  = ht  + (size_t)HS * BS;            // [3H][B]
  float* ght  = gxt + (size_t)3 * HS * BS;        // [3H][B]
  float* hnt  = ght + (size_t)3 * HS * BS;        // [H][B]
  float* qrow = hnt + (size_t)HS * BS;            // [B][H]
  float* scr  = qrow + (size_t)HS * BS;           // [B][S]
  float* mch  = scr + (size_t)BS * SS;            // [B][NCH]
  float* lch  = mch + (size_t)BS * NCH;           // [B][NCH]
  float* ctxp = lch + (size_t)BS * NCH;           // [B*NCH][H]
  float* ctxt = ctxp + (size_t)BS * NCH * HS;     // [H][B]
  float* cot  = ctxt + (size_t)HS * BS;           // [H][B]

  k_gather <<<dim3(HS * BS / 256), dim3(256), 0, stream>>>(idx, emb, hid, xt, ht);
  k_gates  <<<dim3(384, 2), dim3(256), 0, stream>>>(xt, ht, w_ih, w_hh, b_ih, b_hh, gxt, ght);
  k_hnew   <<<dim3(HS * BS / 256), dim3(256), 0, stream>>>(gxt, ght, ht, hnt, out_h);
  k_q      <<<dim3(HS / 8), dim3(256), 0, stream>>>(hnt, aw, qrow);
  k_attn   <<<dim3(BS * NCH / 4), dim3(256), 0, stream>>>(enc, qrow, scr, mch, lch, ctxp);
  k_combine<<<dim3(BS, 4), dim3(256), 0, stream>>>(mch, lch, ctxp, scr, ctxt, out_w);
  k_concat <<<dim3(HS / 8), dim3(256), 0, stream>>>(hnt, ctxt, cw, cb, cot);
  k_out    <<<dim3(VS / 16), dim3(256), 0, stream>>>(cot, ow, ob, out0);
}

// Round 3
// 277.288 us; speedup vs baseline: 3.2331x; 2.9335x over previous
//
#include <hip/hip_runtime.h>

#define HS 1024
#define VS 32000
#define BS 64
#define SS 2048
#define NCH 64
#define SCH (SS/NCH)   // 32 seq positions per wave-chunk

typedef __attribute__((ext_vector_type(4))) float f4v;
typedef __attribute__((ext_vector_type(8))) short s8v;

__device__ __forceinline__ float sigmf(float x) { return 1.0f / (1.0f + __expf(-x)); }

// fp32 -> bf16 (round-to-nearest-even), returned as raw short bits
__device__ __forceinline__ short bf16c(float f) {
  unsigned u = __builtin_bit_cast(unsigned, f);
  u = (u + 0x7FFFu + ((u >> 16) & 1u)) >> 16;
  return (short)u;
}

// ---------------------------------------------------------------------------
// 1. Embedding gather + transpose of x and h into [feature][batch] layout
// ---------------------------------------------------------------------------
__global__ __launch_bounds__(256) void k_gather(const int* __restrict__ idx,
    const float* __restrict__ emb, const float* __restrict__ hid,
    float* __restrict__ xt, float* __restrict__ ht) {
  int tid = blockIdx.x * 256 + threadIdx.x;   // H*B = 65536 threads
  int b = tid >> 10, k = tid & 1023;
  xt[k * BS + b] = emb[(size_t)idx[b] * HS + k];
  ht[k * BS + b] = hid[(size_t)b * HS + k];
}

// ---------------------------------------------------------------------------
// 1b. Swizzle a [K][64] fp32 matrix into MFMA B-fragment layout (bf16).
//     frag element ((kt*4+ct)*64+lane)*8+j  =  src[kt*32+(lane>>4)*8+j][ct*16+(lane&15)]
// ---------------------------------------------------------------------------
__global__ __launch_bounds__(256) void k_swz(const float* __restrict__ src,
    short* __restrict__ dst) {
  int t = blockIdx.x * 256 + threadIdx.x;     // K/32 * 4 * 64 threads
  int lane = t & 63;
  int ct = (t >> 6) & 3;
  int kt = t >> 8;
  int kr = kt * 32 + (lane >> 4) * 8;
  int col = ct * 16 + (lane & 15);
  const float* sp = src + (size_t)kr * BS + col;
  s8v v;
#pragma unroll
  for (int j = 0; j < 8; j++) v[j] = bf16c(sp[j * BS]);
  *(s8v*)(dst + (size_t)t * 8) = v;
}

// ---------------------------------------------------------------------------
// 2. MFMA GEMM: dst[M][64] = W[M][K] (fp32, cast to bf16 in-register) @ X,
//    X pre-swizzled bf16 frags. Block = 64 rows (4 waves x 16). Two pointer
//    sets selectable by blockIdx.y (for the two GRU gate GEMMs).
//    EPI: 0 = bias, 1 = bias+tanh.  OL: 0 = dst[row*64+col], 1 = dst[col*VS+row]
// ---------------------------------------------------------------------------
template<int K, int EPI, int OL>
__global__ __launch_bounds__(256) void mf_gemm(
    const float* __restrict__ W0, const short* __restrict__ xf0,
    const float* __restrict__ b0, float* __restrict__ d0,
    const float* __restrict__ W1, const short* __restrict__ xf1,
    const float* __restrict__ b1, float* __restrict__ d1) {
  const float* W  = blockIdx.y ? W1 : W0;
  const short* xf = blockIdx.y ? xf1 : xf0;
  const float* bias = blockIdx.y ? b1 : b0;
  float* dst = blockIdx.y ? d1 : d0;

  int lane = threadIdx.x & 63;
  int wv = threadIdx.x >> 6;
  int r0 = blockIdx.x * 64 + wv * 16;
  int row = r0 + (lane & 15);
  const float* wp = W + (size_t)row * K + ((lane >> 4) * 8);
  const s8v* xp = (const s8v*)xf + lane;

  f4v acc0 = {0,0,0,0}, acc1 = {0,0,0,0}, acc2 = {0,0,0,0}, acc3 = {0,0,0,0};
#pragma unroll 4
  for (int kt = 0; kt < K / 32; kt++) {
    float4 wa = *(const float4*)(wp + (size_t)kt * 32);
    float4 wb = *(const float4*)(wp + (size_t)kt * 32 + 4);
    s8v a;
    a[0] = bf16c(wa.x); a[1] = bf16c(wa.y); a[2] = bf16c(wa.z); a[3] = bf16c(wa.w);
    a[4] = bf16c(wb.x); a[5] = bf16c(wb.y); a[6] = bf16c(wb.z); a[7] = bf16c(wb.w);
    const s8v* xk = xp + (size_t)kt * 256;
    acc0 = __builtin_amdgcn_mfma_f32_16x16x32_bf16(a, xk[0],   acc0, 0, 0, 0);
    acc1 = __builtin_amdgcn_mfma_f32_16x16x32_bf16(a, xk[64],  acc1, 0, 0, 0);
    acc2 = __builtin_amdgcn_mfma_f32_16x16x32_bf16(a, xk[128], acc2, 0, 0, 0);
    acc3 = __builtin_amdgcn_mfma_f32_16x16x32_bf16(a, xk[192], acc3, 0, 0, 0);
  }
  // D layout: col = lane&15 (+16*ct), row = r0 + (lane>>4)*4 + r
  int rr0 = r0 + (lane >> 4) * 4;
  int cb = lane & 15;
#pragma unroll
  for (int r = 0; r < 4; r++) {
    float bv = bias[rr0 + r];
    float v0 = acc0[r] + bv, v1 = acc1[r] + bv, v2 = acc2[r] + bv, v3 = acc3[r] + bv;
    if (EPI == 1) { v0 = tanhf(v0); v1 = tanhf(v1); v2 = tanhf(v2); v3 = tanhf(v3); }
    if (OL == 0) {
      float* dp = dst + (size_t)(rr0 + r) * BS + cb;
      dp[0] = v0; dp[16] = v1; dp[32] = v2; dp[48] = v3;
    } else {
      dst[(size_t)(cb     ) * VS + rr0 + r] = v0;
      dst[(size_t)(cb + 16) * VS + rr0 + r] = v1;
      dst[(size_t)(cb + 32) * VS + rr0 + r] = v2;
      dst[(size_t)(cb + 48) * VS + rr0 + r] = v3;
    }
  }
}

// ---------------------------------------------------------------------------
// 3. GRU nonlinearity -> h_new (transposed ws copy + [1,B,H] output)
// ---------------------------------------------------------------------------
__global__ __launch_bounds__(256) void k_hnew(const float* __restrict__ gxt,
    const float* __restrict__ ght, const float* __restrict__ ht,
    float* __restrict__ hnt, float* __restrict__ out_h) {
  int tid = blockIdx.x * 256 + threadIdx.x;   // 65536
  int b = tid & 63, i = tid >> 6;
  float r = sigmf(gxt[i * BS + b] + ght[i * BS + b]);
  float z = sigmf(gxt[(HS + i) * BS + b] + ght[(HS + i) * BS + b]);
  float n = tanhf(gxt[(2 * HS + i) * BS + b] + r * ght[(2 * HS + i) * BS + b]);
  float hv = ht[i * BS + b];
  float hn = (1.0f - z) * n + z * hv;
  hnt[i * BS + b] = hn;
  out_h[b * HS + i] = hn;
}

// ---------------------------------------------------------------------------
// 4. q = h_new @ attn_w, row layout qrow[b][p]. Split-K fp32 (aw is k-major
//    for this product, unsuitable for the MFMA A-path). attn_b dropped:
//    per-b constant on every score -> cancels in softmax; scores not output.
// ---------------------------------------------------------------------------
__global__ __launch_bounds__(256) void k_q(const float* __restrict__ hnt,
    const float* __restrict__ aw, float* __restrict__ qrow) {
  int lane = threadIdx.x & 63;
  int wv = __builtin_amdgcn_readfirstlane(threadIdx.x >> 6);
  int p0 = blockIdx.x * 8;
  int g0 = wv * 256;
  float acc[8] = {0.f, 0.f, 0.f, 0.f, 0.f, 0.f, 0.f, 0.f};
  for (int g = g0; g < g0 + 256; g += 2) {
    float h0v = hnt[g * BS + lane];
    float h1v = hnt[(g + 1) * BS + lane];
    const float* a0p = aw + (size_t)g * HS + p0;
    const float* a1p = a0p + HS;
#pragma unroll
    for (int jj = 0; jj < 8; jj++)
      acc[jj] = fmaf(a0p[jj], h0v, fmaf(a1p[jj], h1v, acc[jj]));
  }
  __shared__ float red[4][8][64];
#pragma unroll
  for (int jj = 0; jj < 8; jj++) red[wv][jj][lane] = acc[jj];
  __syncthreads();
  float2 qv;
  {
    int jj = wv * 2;
    qv.x = red[0][jj][lane] + red[1][jj][lane] + red[2][jj][lane] + red[3][jj][lane];
    jj++;
    qv.y = red[0][jj][lane] + red[1][jj][lane] + red[2][jj][lane] + red[3][jj][lane];
  }
  *(float2*)(qrow + (size_t)lane * HS + p0 + wv * 2) = qv;
}

// ---------------------------------------------------------------------------
// 5. Fused scores + online softmax + context: ONE WAVE per (b, chunk).
// ---------------------------------------------------------------------------
__global__ __launch_bounds__(256) void k_attn(const float* __restrict__ enc,
    const float* __restrict__ qrow, float* __restrict__ scores,
    float* __restrict__ mch, float* __restrict__ lch, float* __restrict__ ctxp) {
  int lane = threadIdx.x & 63;
  int w = blockIdx.x * 4 + (threadIdx.x >> 6);   // 4096 waves
  int b = w & 63;
  int ch = w >> 6;                               // 0..63
  const float* qb = qrow + (size_t)b * HS;
  float4 q0 = *(const float4*)(qb + 0   + lane * 4);
  float4 q1 = *(const float4*)(qb + 256 + lane * 4);
  float4 q2 = *(const float4*)(qb + 512 + lane * 4);
  float4 q3 = *(const float4*)(qb + 768 + lane * 4);
  int s0 = ch * SCH;
  const float* ep = enc + ((size_t)s0 * BS + b) * HS;
  float4 e0 = *(const float4*)(ep + 0   + lane * 4);
  float4 e1 = *(const float4*)(ep + 256 + lane * 4);
  float4 e2 = *(const float4*)(ep + 512 + lane * 4);
  float4 e3 = *(const float4*)(ep + 768 + lane * 4);
  float m = -1e30f, l = 0.f;
  float4 a0 = {0,0,0,0}, a1 = {0,0,0,0}, a2 = {0,0,0,0}, a3 = {0,0,0,0};
  for (int si = 0; si < SCH; si++) {
    float4 c0 = e0, c1 = e1, c2 = e2, c3 = e3;
    if (si + 1 < SCH) {
      const float* np = ep + (size_t)BS * HS;
      e0 = *(const float4*)(np + 0   + lane * 4);
      e1 = *(const float4*)(np + 256 + lane * 4);
      e2 = *(const float4*)(np + 512 + lane * 4);
      e3 = *(const float4*)(np + 768 + lane * 4);
    }
    ep += (size_t)BS * HS;
    float d0 = fmaf(c0.x, q0.x, fmaf(c0.y, q0.y, fmaf(c0.z, q0.z, c0.w * q0.w)));
    float d1 = fmaf(c1.x, q1.x, fmaf(c1.y, q1.y, fmaf(c1.z, q1.z, c1.w * q1.w)));
    float d2 = fmaf(c2.x, q2.x, fmaf(c2.y, q2.y, fmaf(c2.z, q2.z, c2.w * q2.w)));
    float d3 = fmaf(c3.x, q3.x, fmaf(c3.y, q3.y, fmaf(c3.z, q3.z, c3.w * q3.w)));
    float p = (d0 + d1) + (d2 + d3);
#pragma unroll
    for (int off = 32; off; off >>= 1) p += __shfl_xor(p, off, 64);
    if (lane == 0) scores[(size_t)b * SS + s0 + si] = p;
    float mn = fmaxf(m, p);
    float sc = __expf(m - mn);
    float pr = __expf(p - mn);
    l = fmaf(l, sc, pr);
    a0.x = fmaf(a0.x, sc, pr * c0.x); a0.y = fmaf(a0.y, sc, pr * c0.y);
    a0.z = fmaf(a0.z, sc, pr * c0.z); a0.w = fmaf(a0.w, sc, pr * c0.w);
    a1.x = fmaf(a1.x, sc, pr * c1.x); a1.y = fmaf(a1.y, sc, pr * c1.y);
    a1.z = fmaf(a1.z, sc, pr * c1.z); a1.w = fmaf(a1.w, sc, pr * c1.w);
    a2.x = fmaf(a2.x, sc, pr * c2.x); a2.y = fmaf(a2.y, sc, pr * c2.y);
    a2.z = fmaf(a2.z, sc, pr * c2.z); a2.w = fmaf(a2.w, sc, pr * c2.w);
    a3.x = fmaf(a3.x, sc, pr * c3.x); a3.y = fmaf(a3.y, sc, pr * c3.y);
    a3.z = fmaf(a3.z, sc, pr * c3.z); a3.w = fmaf(a3.w, sc, pr * c3.w);
    m = mn;
  }
  if (lane == 0) { mch[b * NCH + ch] = m; lch[b * NCH + ch] = l; }
  float* cp = ctxp + ((size_t)(b * NCH + ch)) * HS;
  *(float4*)(cp + 0   + lane * 4) = a0;
  *(float4*)(cp + 256 + lane * 4) = a1;
  *(float4*)(cp + 512 + lane * 4) = a2;
  *(float4*)(cp + 768 + lane * 4) = a3;
}

// ---------------------------------------------------------------------------
// 6. Combine chunk partials -> context (transposed) + softmax weights output
// ---------------------------------------------------------------------------
__global__ __launch_bounds__(256) void k_combine(const float* __restrict__ mch,
    const float* __restrict__ lch, const float* __restrict__ ctxp,
    const float* __restrict__ scores, float* __restrict__ ctxt,
    float* __restrict__ wout) {
  int b = blockIdx.x;
  int t = threadIdx.x;
  __shared__ float sm[NCH], sl[NCH], ssc[NCH];
  if (t < NCH) { sm[t] = mch[b * NCH + t]; sl[t] = lch[b * NCH + t]; }
  __syncthreads();
  float mstar = -1e30f;
  for (int c = 0; c < NCH; c++) mstar = fmaxf(mstar, sm[c]);
  if (t < NCH) ssc[t] = __expf(sm[t] - mstar);
  __syncthreads();
  float L = 0.f;
  for (int c = 0; c < NCH; c++) L = fmaf(sl[c], ssc[c], L);
  float invL = 1.0f / L;
  int h = blockIdx.y * 256 + t;
  float acc = 0.f;
  for (int c = 0; c < NCH; c++)
    acc = fmaf(ctxp[((size_t)(b * NCH + c)) * HS + h], ssc[c], acc);
  ctxt[h * BS + b] = acc * invL;
  if (blockIdx.y == 0)
    for (int s = t; s < SS; s += 256)
      wout[(size_t)b * SS + s] = __expf(scores[(size_t)b * SS + s] - mstar) * invL;
}

// ---------------------------------------------------------------------------
extern "C" void kernel_launch(void* const* d_in, const int* in_sizes, int n_in,
                              void* d_out, int out_size, void* d_ws, size_t ws_size,
                              hipStream_t stream) {
  const int*   idx  = (const int*)d_in[0];
  const float* hid  = (const float*)d_in[1];
  const float* enc  = (const float*)d_in[2];
  const float* emb  = (const float*)d_in[3];
  const float* w_ih = (const float*)d_in[4];
  const float* w_hh = (const float*)d_in[5];
  const float* b_ih = (const float*)d_in[6];
  const float* b_hh = (const float*)d_in[7];
  const float* aw   = (const float*)d_in[8];
  // d_in[9] = attn_b: per-b constant on every score -> cancels in softmax.
  const float* cw   = (const float*)d_in[10];
  const float* cb   = (const float*)d_in[11];
  const float* ow   = (const float*)d_in[12];
  const float* ob   = (const float*)d_in[13];

  float* out0  = (float*)d_out;                   // [B, V]
  float* out_h = out0 + (size_t)BS * VS;          // [1, B, H]
  float* out_w = out_h + (size_t)BS * HS;         // [B, 1, S]

  // workspace layout (floats); ~20.2 MB total (same footprint as before)
  float* ws   = (float*)d_ws;
  float* xt   = ws;                               // [H][B]
  float* ht   = xt  + (size_t)HS * BS;            // [H][B]
  float* gxt  = ht  + (size_t)HS * BS;            // [3H][B]
  float* ght  = gxt + (size_t)3 * HS * BS;        // [3H][B]
  float* hnt  = ght + (size_t)3 * HS * BS;        // [H][B]
  float* ctxt = hnt + (size_t)HS * BS;            // [H][B] (contiguous after hnt!)
  float* qrow = ctxt + (size_t)HS * BS;           // [B][H]
  float* scr  = qrow + (size_t)HS * BS;           // [B][S]
  float* mch  = scr + (size_t)BS * SS;            // [B][NCH]
  float* lch  = mch + (size_t)BS * NCH;           // [B][NCH]
  float* ctxp = lch + (size_t)BS * NCH;           // [B*NCH][H]  (16 MB)
  float* cot  = ctxp + (size_t)BS * NCH * HS;     // [H][B]

  // bf16 fragment buffers ALIAS ctxp (liveness-disjoint):
  //   fx/fh: written+read before k_attn writes ctxp.
  //   fcat/fc: written after k_combine's last read of ctxp.
  short* fx   = (short*)ctxp;                     // 64K shorts (K=1024)
  short* fh   = fx   + (size_t)HS * BS;           // 64K shorts
  short* fcat = fh   + (size_t)HS * BS;           // 128K shorts (K=2048)
  short* fc   = fcat + (size_t)2 * HS * BS;       // 64K shorts

  k_gather <<<dim3(HS * BS / 256), dim3(256), 0, stream>>>(idx, emb, hid, xt, ht);
  k_swz    <<<dim3(HS / 32), dim3(256), 0, stream>>>(xt, fx);
  k_swz    <<<dim3(HS / 32), dim3(256), 0, stream>>>(ht, fh);
  mf_gemm<HS, 0, 0><<<dim3(3 * HS / 64, 2), dim3(256), 0, stream>>>(
      w_ih, fx, b_ih, gxt, w_hh, fh, b_hh, ght);
  k_hnew   <<<dim3(HS * BS / 256), dim3(256), 0, stream>>>(gxt, ght, ht, hnt, out_h);
  k_q      <<<dim3(HS / 8), dim3(256), 0, stream>>>(hnt, aw, qrow);
  k_attn   <<<dim3(BS * NCH / 4), dim3(256), 0, stream>>>(enc, qrow, scr, mch, lch, ctxp);
  k_combine<<<dim3(BS, 4), dim3(256), 0, stream>>>(mch, lch, ctxp, scr, ctxt, out_w);
  k_swz    <<<dim3(2 * HS / 32), dim3(256), 0, stream>>>(hnt, fcat);   // [hnt;ctxt]
  mf_gemm<2 * HS, 1, 0><<<dim3(HS / 64, 1), dim3(256), 0, stream>>>(
      cw, fcat, cb, cot, cw, fcat, cb, cot);
  k_swz    <<<dim3(HS / 32), dim3(256), 0, stream>>>(cot, fc);
  mf_gemm<HS, 0, 1><<<dim3(VS / 64, 1), dim3(256), 0, stream>>>(
      ow, fc, ob, out0, ow, fc, ob, out0);
}

// Round 4
// 255.262 us; speedup vs baseline: 3.5121x; 1.0863x over previous
//
#include <hip/hip_runtime.h>

#define HS 1024
#define VS 32000
#define BS 64
#define SS 2048
#define NCH 128
#define SCH (SS/NCH)   // 16 seq positions per wave-chunk

typedef __attribute__((ext_vector_type(4))) float f4v;
typedef __attribute__((ext_vector_type(8))) short s8v;

__device__ __forceinline__ float sigmf(float x) { return 1.0f / (1.0f + __expf(-x)); }

// fp32 -> bf16 (round-to-nearest-even), raw short bits
__device__ __forceinline__ short bf16c(float f) {
  unsigned u = __builtin_bit_cast(unsigned, f);
  u = (u + 0x7FFFu + ((u >> 16) & 1u)) >> 16;
  return (short)u;
}

// ---------------------------------------------------------------------------
// 1. prep: (a) swizzle aw [K=1024][N=1024] into MFMA B-frags (awf),
//    (b) gather ht [k][b] from hid, (c) build fx/fh B-frags (N=64) straight
//    from emb/hid (j-stride contiguous -> coalesced 32B reads).
//    Frag layouts: N=64:  idx = ((kt*4  + ct)*64 + lane)*8 + j
//                  N=1024: idx = ((kt*64 + nt)*64 + lane)*8 + j
//    element = src[kt*32 + (lane>>4)*8 + j][tile*16 + (lane&15)]
// ---------------------------------------------------------------------------
__global__ __launch_bounds__(256) void k_prep(const int* __restrict__ idx,
    const float* __restrict__ emb, const float* __restrict__ hid,
    const float* __restrict__ aw, float* __restrict__ ht,
    short* __restrict__ fx, short* __restrict__ fh, short* __restrict__ awf) {
  int t = blockIdx.x * 256 + threadIdx.x;   // 131072 threads
  { // awf
    int lane = t & 63, nt = (t >> 6) & 63, kt = t >> 12;   // kt 0..31
    int kr = kt * 32 + ((lane >> 4) & 3) * 8;
    int col = nt * 16 + (lane & 15);
    const float* sp = aw + (size_t)kr * HS + col;
    s8v v;
#pragma unroll
    for (int j = 0; j < 8; j++) v[j] = bf16c(sp[(size_t)j * HS]);
    *(s8v*)(awf + (size_t)t * 8) = v;
  }
  if (t < 65536) { // ht gather (coalesced hid row reads)
    int b = t >> 10, k = t & 1023;
    ht[k * BS + b] = hid[(size_t)b * HS + k];
  }
  if (t < 8192) { // fx from emb via idx
    int lane = t & 63, ct = (t >> 6) & 3, kt = t >> 8;
    int col = ct * 16 + (lane & 15);
    int kr = kt * 32 + ((lane >> 4) & 3) * 8;
    const float* sp = emb + (size_t)idx[col] * HS + kr;
    s8v v;
#pragma unroll
    for (int j = 0; j < 8; j++) v[j] = bf16c(sp[j]);
    *(s8v*)(fx + (size_t)t * 8) = v;
  } else if (t < 16384) { // fh from hid
    int t2 = t - 8192;
    int lane = t2 & 63, ct = (t2 >> 6) & 3, kt = t2 >> 8;
    int col = ct * 16 + (lane & 15);
    int kr = kt * 32 + ((lane >> 4) & 3) * 8;
    const float* sp = hid + (size_t)col * HS + kr;
    s8v v;
#pragma unroll
    for (int j = 0; j < 8; j++) v[j] = bf16c(sp[j]);
    *(s8v*)(fh + (size_t)t2 * 8) = v;
  }
}

// ---------------------------------------------------------------------------
// 2. Split-K MFMA GEMM: dst[M][64] = W[M][K]@X. Block = one 16-row m-tile;
//    4 waves each own K/4; LDS combine. OL 0: fp32 dst[row*64+col] (gates).
//    OL 1: tanh -> bf16 dst[col*HS+row] (concat -> cbf).
// ---------------------------------------------------------------------------
template<int K, int OL>
__global__ __launch_bounds__(256) void mfsk(
    const float* __restrict__ W0, const short* __restrict__ xf0,
    const float* __restrict__ bias0, void* __restrict__ dst0,
    const float* __restrict__ W1, const short* __restrict__ xf1,
    const float* __restrict__ bias1, void* __restrict__ dst1) {
  const float* W    = blockIdx.y ? W1 : W0;
  const short* xf   = blockIdx.y ? xf1 : xf0;
  const float* bias = blockIdx.y ? bias1 : bias0;
  void* dst         = blockIdx.y ? dst1 : dst0;
  int lane = threadIdx.x & 63;
  int ks = threadIdx.x >> 6;           // k-slice 0..3
  int mt = blockIdx.x;                 // 16-row tile
  int row = mt * 16 + (lane & 15);
  const int KW = (K / 32) / 4;         // k-tiles per wave
  const float* wp = W + (size_t)row * K + ((lane >> 4) * 8);
  const s8v* xp = (const s8v*)xf + lane;
  f4v acc0 = {0,0,0,0}, acc1 = {0,0,0,0}, acc2 = {0,0,0,0}, acc3 = {0,0,0,0};
#pragma unroll 4
  for (int kk = 0; kk < KW; kk++) {
    int kt = ks * KW + kk;
    float4 wa = *(const float4*)(wp + (size_t)kt * 32);
    float4 wb = *(const float4*)(wp + (size_t)kt * 32 + 4);
    s8v a;
    a[0] = bf16c(wa.x); a[1] = bf16c(wa.y); a[2] = bf16c(wa.z); a[3] = bf16c(wa.w);
    a[4] = bf16c(wb.x); a[5] = bf16c(wb.y); a[6] = bf16c(wb.z); a[7] = bf16c(wb.w);
    const s8v* xk = xp + (size_t)kt * 256;
    acc0 = __builtin_amdgcn_mfma_f32_16x16x32_bf16(a, xk[0],   acc0, 0, 0, 0);
    acc1 = __builtin_amdgcn_mfma_f32_16x16x32_bf16(a, xk[64],  acc1, 0, 0, 0);
    acc2 = __builtin_amdgcn_mfma_f32_16x16x32_bf16(a, xk[128], acc2, 0, 0, 0);
    acc3 = __builtin_amdgcn_mfma_f32_16x16x32_bf16(a, xk[192], acc3, 0, 0, 0);
  }
  __shared__ float red[4][4][4][64];   // [ks][ct][r][lane] = 16 KB
#pragma unroll
  for (int r = 0; r < 4; r++) {
    red[ks][0][r][lane] = acc0[r];
    red[ks][1][r][lane] = acc1[r];
    red[ks][2][r][lane] = acc2[r];
    red[ks][3][r][lane] = acc3[r];
  }
  __syncthreads();
  int ct = ks;
  int rr0 = mt * 16 + (lane >> 4) * 4;
  int col = ct * 16 + (lane & 15);
#pragma unroll
  for (int r = 0; r < 4; r++) {
    float v = red[0][ct][r][lane] + red[1][ct][r][lane] +
              red[2][ct][r][lane] + red[3][ct][r][lane] + bias[rr0 + r];
    if (OL == 0)
      ((float*)dst)[(size_t)(rr0 + r) * BS + col] = v;
    else
      ((short*)dst)[(size_t)col * HS + rr0 + r] = bf16c(tanhf(v));
  }
}

// ---------------------------------------------------------------------------
// 3. GRU nonlinearity -> out_h [1,B,H] + fcat-low bf16 frags (k=i, col=b)
// ---------------------------------------------------------------------------
__global__ __launch_bounds__(256) void k_hnew(const float* __restrict__ gxt,
    const float* __restrict__ ght, const float* __restrict__ ht,
    float* __restrict__ out_h, short* __restrict__ fcat) {
  int tid = blockIdx.x * 256 + threadIdx.x;   // 65536
  int b = tid & 63, i = tid >> 6;
  float r = sigmf(gxt[i * BS + b] + ght[i * BS + b]);
  float z = sigmf(gxt[(HS + i) * BS + b] + ght[(HS + i) * BS + b]);
  float n = tanhf(gxt[(2 * HS + i) * BS + b] + r * ght[(2 * HS + i) * BS + b]);
  float hn = (1.0f - z) * n + z * ht[i * BS + b];
  out_h[(size_t)b * HS + i] = hn;
  int kt = i >> 5, j = i & 7;
  int lane = (b & 15) | (((i >> 3) & 3) << 4);
  int ct = b >> 4;
  fcat[((size_t)((kt * 4 + ct) * 64 + lane)) * 8 + j] = bf16c(hn);
}

// ---------------------------------------------------------------------------
// 4. q = h_new @ aw via MFMA. A = out_h [b][g] (row-major, contiguous),
//    B = awf frags. attn_b dropped (per-b constant -> cancels in softmax).
// ---------------------------------------------------------------------------
__global__ __launch_bounds__(256) void k_qgemm(const float* __restrict__ hnr,
    const short* __restrict__ awf, float* __restrict__ qrow) {
  int lane = threadIdx.x & 63;
  int mt = threadIdx.x >> 6;    // b-tile 0..3
  int nt = blockIdx.x;          // h-tile 0..63
  const float* ap = hnr + (size_t)(mt * 16 + (lane & 15)) * HS + ((lane >> 4) * 8);
  const s8v* bp = (const s8v*)awf + (size_t)nt * 64 + lane;
  f4v acc = {0,0,0,0};
#pragma unroll 4
  for (int kt = 0; kt < 32; kt++) {
    float4 wa = *(const float4*)(ap + kt * 32);
    float4 wb = *(const float4*)(ap + kt * 32 + 4);
    s8v a;
    a[0] = bf16c(wa.x); a[1] = bf16c(wa.y); a[2] = bf16c(wa.z); a[3] = bf16c(wa.w);
    a[4] = bf16c(wb.x); a[5] = bf16c(wb.y); a[6] = bf16c(wb.z); a[7] = bf16c(wb.w);
    acc = __builtin_amdgcn_mfma_f32_16x16x32_bf16(a, bp[(size_t)kt * 4096], acc, 0, 0, 0);
  }
  int r0 = mt * 16 + (lane >> 4) * 4;
  int hcol = nt * 16 + (lane & 15);
#pragma unroll
  for (int r = 0; r < 4; r++)
    qrow[(size_t)(r0 + r) * HS + hcol] = acc[r];
}

// ---------------------------------------------------------------------------
// 5. Fused scores + online softmax + context: ONE WAVE per (b, chunk),
//    2 seq positions per iteration (dual butterflies, one rescale/pair).
// ---------------------------------------------------------------------------
__global__ __launch_bounds__(256) void k_attn(const float* __restrict__ enc,
    const float* __restrict__ qrow, float* __restrict__ scores,
    float* __restrict__ mch, float* __restrict__ lch, float* __restrict__ ctxp) {
  int lane = threadIdx.x & 63;
  int w = blockIdx.x * 4 + (threadIdx.x >> 6);   // 8192 waves
  int b = w & 63;
  int ch = w >> 6;                               // 0..127
  const float* qb = qrow + (size_t)b * HS + lane * 4;
  float4 q0 = *(const float4*)(qb + 0);
  float4 q1 = *(const float4*)(qb + 256);
  float4 q2 = *(const float4*)(qb + 512);
  float4 q3 = *(const float4*)(qb + 768);
  int s0 = ch * SCH;
  const size_t sstr = (size_t)BS * HS;
  const float* ep = enc + ((size_t)s0 * BS + b) * HS + lane * 4;
  float4 eb[2][8];
#pragma unroll
  for (int u = 0; u < 2; u++) {
    eb[0][u * 4 + 0] = *(const float4*)(ep + u * sstr + 0);
    eb[0][u * 4 + 1] = *(const float4*)(ep + u * sstr + 256);
    eb[0][u * 4 + 2] = *(const float4*)(ep + u * sstr + 512);
    eb[0][u * 4 + 3] = *(const float4*)(ep + u * sstr + 768);
  }
  float m = -1e30f, l = 0.f;
  float4 a0 = {0,0,0,0}, a1 = {0,0,0,0}, a2 = {0,0,0,0}, a3 = {0,0,0,0};
#pragma unroll
  for (int it = 0; it < SCH / 2; it++) {
    const int cur = it & 1, nxt = cur ^ 1;
    if (it + 1 < SCH / 2) {
      const float* np = ep + (size_t)(2 * it + 2) * sstr;
#pragma unroll
      for (int u = 0; u < 2; u++) {
        eb[nxt][u * 4 + 0] = *(const float4*)(np + u * sstr + 0);
        eb[nxt][u * 4 + 1] = *(const float4*)(np + u * sstr + 256);
        eb[nxt][u * 4 + 2] = *(const float4*)(np + u * sstr + 512);
        eb[nxt][u * 4 + 3] = *(const float4*)(np + u * sstr + 768);
      }
    }
    float4 c0 = eb[cur][0], c1 = eb[cur][1], c2 = eb[cur][2], c3 = eb[cur][3];
    float4 c4 = eb[cur][4], c5 = eb[cur][5], c6 = eb[cur][6], c7 = eb[cur][7];
    float d0 = fmaf(c0.x,q0.x, fmaf(c0.y,q0.y, fmaf(c0.z,q0.z, c0.w*q0.w)));
    float d1 = fmaf(c1.x,q1.x, fmaf(c1.y,q1.y, fmaf(c1.z,q1.z, c1.w*q1.w)));
    float d2 = fmaf(c2.x,q2.x, fmaf(c2.y,q2.y, fmaf(c2.z,q2.z, c2.w*q2.w)));
    float d3 = fmaf(c3.x,q3.x, fmaf(c3.y,q3.y, fmaf(c3.z,q3.z, c3.w*q3.w)));
    float pa = (d0 + d1) + (d2 + d3);
    float e0 = fmaf(c4.x,q0.x, fmaf(c4.y,q0.y, fmaf(c4.z,q0.z, c4.w*q0.w)));
    float e1 = fmaf(c5.x,q1.x, fmaf(c5.y,q1.y, fmaf(c5.z,q1.z, c5.w*q1.w)));
    float e2 = fmaf(c6.x,q2.x, fmaf(c6.y,q2.y, fmaf(c6.z,q2.z, c6.w*q2.w)));
    float e3 = fmaf(c7.x,q3.x, fmaf(c7.y,q3.y, fmaf(c7.z,q3.z, c7.w*q3.w)));
    float pb = (e0 + e1) + (e2 + e3);
#pragma unroll
    for (int off = 32; off; off >>= 1) {
      pa += __shfl_xor(pa, off, 64);
      pb += __shfl_xor(pb, off, 64);
    }
    if (lane == 0) {
      scores[(size_t)b * SS + s0 + 2 * it]     = pa;
      scores[(size_t)b * SS + s0 + 2 * it + 1] = pb;
    }
    float mn = fmaxf(m, fmaxf(pa, pb));
    float sc  = __expf(m - mn);     // first iter: exp(-huge) = 0
    float pra = __expf(pa - mn);
    float prb = __expf(pb - mn);
    l = fmaf(l, sc, pra + prb);
    a0.x = fmaf(a0.x, sc, fmaf(pra, c0.x, prb * c4.x));
    a0.y = fmaf(a0.y, sc, fmaf(pra, c0.y, prb * c4.y));
    a0.z = fmaf(a0.z, sc, fmaf(pra, c0.z, prb * c4.z));
    a0.w = fmaf(a0.w, sc, fmaf(pra, c0.w, prb * c4.w));
    a1.x = fmaf(a1.x, sc, fmaf(pra, c1.x, prb * c5.x));
    a1.y = fmaf(a1.y, sc, fmaf(pra, c1.y, prb * c5.y));
    a1.z = fmaf(a1.z, sc, fmaf(pra, c1.z, prb * c5.z));
    a1.w = fmaf(a1.w, sc, fmaf(pra, c1.w, prb * c5.w));
    a2.x = fmaf(a2.x, sc, fmaf(pra, c2.x, prb * c6.x));
    a2.y = fmaf(a2.y, sc, fmaf(pra, c2.y, prb * c6.y));
    a2.z = fmaf(a2.z, sc, fmaf(pra, c2.z, prb * c6.z));
    a2.w = fmaf(a2.w, sc, fmaf(pra, c2.w, prb * c6.w));
    a3.x = fmaf(a3.x, sc, fmaf(pra, c3.x, prb * c7.x));
    a3.y = fmaf(a3.y, sc, fmaf(pra, c3.y, prb * c7.y));
    a3.z = fmaf(a3.z, sc, fmaf(pra, c3.z, prb * c7.z));
    a3.w = fmaf(a3.w, sc, fmaf(pra, c3.w, prb * c7.w));
    m = mn;
  }
  if (lane == 0) { mch[b * NCH + ch] = m; lch[b * NCH + ch] = l; }
  float* cp = ctxp + ((size_t)(b * NCH + ch)) * HS + lane * 4;
  *(float4*)(cp + 0)   = a0;
  *(float4*)(cp + 256) = a1;
  *(float4*)(cp + 512) = a2;
  *(float4*)(cp + 768) = a3;
}

// ---------------------------------------------------------------------------
// 6. Combine chunk partials -> fcat-high bf16 frags + softmax weights output
// ---------------------------------------------------------------------------
__global__ __launch_bounds__(256) void k_combine(const float* __restrict__ mch,
    const float* __restrict__ lch, const float* __restrict__ ctxp,
    const float* __restrict__ scores, short* __restrict__ fcat,
    float* __restrict__ wout) {
  int b = blockIdx.x;
  int t = threadIdx.x;
  __shared__ float sm[NCH], sl[NCH], ssc[NCH];
  if (t < NCH) { sm[t] = mch[b * NCH + t]; sl[t] = lch[b * NCH + t]; }
  __syncthreads();
  float mstar = -1e30f;
  for (int c = 0; c < NCH; c++) mstar = fmaxf(mstar, sm[c]);
  if (t < NCH) ssc[t] = __expf(sm[t] - mstar);
  __syncthreads();
  float L = 0.f;
  for (int c = 0; c < NCH; c++) L = fmaf(sl[c], ssc[c], L);
  float invL = 1.0f / L;
  int h = blockIdx.y * 256 + t;
  float acc = 0.f;
  for (int c = 0; c < NCH; c++)
    acc = fmaf(ctxp[((size_t)(b * NCH + c)) * HS + h], ssc[c], acc);
  float ctx = acc * invL;
  int kc = HS + h;
  int kt = kc >> 5, j = kc & 7;
  int lane2 = (b & 15) | (((kc >> 3) & 3) << 4);
  int ct = b >> 4;
  fcat[((size_t)((kt * 4 + ct) * 64 + lane2)) * 8 + j] = bf16c(ctx);
  if (blockIdx.y == 0)
    for (int s = t; s < SS; s += 256)
      wout[(size_t)b * SS + s] = __expf(scores[(size_t)b * SS + s] - mstar) * invL;
}

// ---------------------------------------------------------------------------
// 7. output = concat_output @ out_w^T + out_b. A = cbf [b][k] bf16 (direct
//    16B frag loads), B = ow rows converted in-register. D[b][v] coalesced.
// ---------------------------------------------------------------------------
__global__ __launch_bounds__(256) void k_out2(const short* __restrict__ cbf,
    const float* __restrict__ ow, const float* __restrict__ ob,
    float* __restrict__ out0) {
  int lane = threadIdx.x & 63;
  int wv = threadIdx.x >> 6;
  int nt = blockIdx.x * 4 + wv;   // 0..1999 v-tiles
  int v0 = nt * 16;
  const float* wp = ow + (size_t)(v0 + (lane & 15)) * HS + ((lane >> 4) * 8);
  const short* a0p = cbf + (size_t)(0  + (lane & 15)) * HS + ((lane >> 4) * 8);
  const short* a1p = a0p + (size_t)16 * HS;
  const short* a2p = a0p + (size_t)32 * HS;
  const short* a3p = a0p + (size_t)48 * HS;
  f4v acc0 = {0,0,0,0}, acc1 = {0,0,0,0}, acc2 = {0,0,0,0}, acc3 = {0,0,0,0};
#pragma unroll 2
  for (int kt = 0; kt < 32; kt++) {
    float4 wa = *(const float4*)(wp + kt * 32);
    float4 wb = *(const float4*)(wp + kt * 32 + 4);
    s8v bf;
    bf[0] = bf16c(wa.x); bf[1] = bf16c(wa.y); bf[2] = bf16c(wa.z); bf[3] = bf16c(wa.w);
    bf[4] = bf16c(wb.x); bf[5] = bf16c(wb.y); bf[6] = bf16c(wb.z); bf[7] = bf16c(wb.w);
    s8v fa0 = *(const s8v*)(a0p + kt * 32);
    s8v fa1 = *(const s8v*)(a1p + kt * 32);
    s8v fa2 = *(const s8v*)(a2p + kt * 32);
    s8v fa3 = *(const s8v*)(a3p + kt * 32);
    acc0 = __builtin_amdgcn_mfma_f32_16x16x32_bf16(fa0, bf, acc0, 0, 0, 0);
    acc1 = __builtin_amdgcn_mfma_f32_16x16x32_bf16(fa1, bf, acc1, 0, 0, 0);
    acc2 = __builtin_amdgcn_mfma_f32_16x16x32_bf16(fa2, bf, acc2, 0, 0, 0);
    acc3 = __builtin_amdgcn_mfma_f32_16x16x32_bf16(fa3, bf, acc3, 0, 0, 0);
  }
  float bv = ob[v0 + (lane & 15)];
  int rb = (lane >> 4) * 4;
  int vc = v0 + (lane & 15);
#pragma unroll
  for (int r = 0; r < 4; r++) {
    out0[(size_t)(0  + rb + r) * VS + vc] = acc0[r] + bv;
    out0[(size_t)(16 + rb + r) * VS + vc] = acc1[r] + bv;
    out0[(size_t)(32 + rb + r) * VS + vc] = acc2[r] + bv;
    out0[(size_t)(48 + rb + r) * VS + vc] = acc3[r] + bv;
  }
}

// ---------------------------------------------------------------------------
extern "C" void kernel_launch(void* const* d_in, const int* in_sizes, int n_in,
                              void* d_out, int out_size, void* d_ws, size_t ws_size,
                              hipStream_t stream) {
  const int*   idx  = (const int*)d_in[0];
  const float* hid  = (const float*)d_in[1];
  const float* enc  = (const float*)d_in[2];
  const float* emb  = (const float*)d_in[3];
  const float* w_ih = (const float*)d_in[4];
  const float* w_hh = (const float*)d_in[5];
  const float* b_ih = (const float*)d_in[6];
  const float* b_hh = (const float*)d_in[7];
  const float* aw   = (const float*)d_in[8];
  // d_in[9] = attn_b: per-b constant on every score -> cancels in softmax.
  const float* cw   = (const float*)d_in[10];
  const float* cb   = (const float*)d_in[11];
  const float* ow   = (const float*)d_in[12];
  const float* ob   = (const float*)d_in[13];

  float* out0  = (float*)d_out;                   // [B, V]
  float* out_h = out0 + (size_t)BS * VS;          // [1, B, H]
  float* out_w = out_h + (size_t)BS * HS;         // [B, 1, S]

  // workspace (~39 MB)
  float* ws   = (float*)d_ws;
  float* gxt  = ws;                               // [3H][B]
  float* ght  = gxt + (size_t)3 * HS * BS;        // [3H][B]
  float* ht   = ght + (size_t)3 * HS * BS;        // [H][B]
  float* qrow = ht  + (size_t)HS * BS;            // [B][H]
  float* scr  = qrow + (size_t)HS * BS;           // [B][S]
  float* mch  = scr + (size_t)BS * SS;            // [B][NCH]
  float* lch  = mch + (size_t)BS * NCH;           // [B][NCH]
  float* ctxp = lch + (size_t)BS * NCH;           // [B*NCH][H]  (32 MB)
  short* awf  = (short*)(ctxp + (size_t)BS * NCH * HS);  // 1M shorts
  short* fx   = awf + (size_t)HS * HS;            // 64K shorts
  short* fh   = fx  + (size_t)HS * BS;            // 64K shorts
  short* fcat = fh  + (size_t)HS * BS;            // 128K shorts
  short* cbf  = fcat + (size_t)2 * HS * BS;       // 64K shorts

  k_prep   <<<dim3(512), dim3(256), 0, stream>>>(idx, emb, hid, aw, ht, fx, fh, awf);
  mfsk<HS, 0><<<dim3(3 * HS / 16, 2), dim3(256), 0, stream>>>(
      w_ih, fx, b_ih, gxt, w_hh, fh, b_hh, ght);
  k_hnew   <<<dim3(HS * BS / 256), dim3(256), 0, stream>>>(gxt, ght, ht, out_h, fcat);
  k_qgemm  <<<dim3(HS / 16), dim3(256), 0, stream>>>(out_h, awf, qrow);
  k_attn   <<<dim3(BS * NCH / 4), dim3(256), 0, stream>>>(enc, qrow, scr, mch, lch, ctxp);
  k_combine<<<dim3(BS, 4), dim3(256), 0, stream>>>(mch, lch, ctxp, scr, fcat, out_w);
  mfsk<2 * HS, 1><<<dim3(HS / 16, 1), dim3(256), 0, stream>>>(
      cw, fcat, cb, cbf, cw, fcat, cb, cbf);
  k_out2   <<<dim3(VS / 64), dim3(256), 0, stream>>>(cbf, ow, ob, out0);
}

// Round 5
// 210.535 us; speedup vs baseline: 4.2582x; 1.2124x over previous
//
#include <hip/hip_runtime.h>

#define HS 1024
#define VS 32000
#define BS 64
#define SS 2048
#define NCH 64
#define SCH (SS/NCH)   // 32 seq positions per wave-chunk

typedef __attribute__((ext_vector_type(4))) float f4v;
typedef __attribute__((ext_vector_type(8))) short s8v;

__device__ __forceinline__ float sigmf(float x) { return 1.0f / (1.0f + __expf(-x)); }

// fp32 -> bf16 (round-to-nearest-even), raw short bits
__device__ __forceinline__ short bf16c(float f) {
  unsigned u = __builtin_bit_cast(unsigned, f);
  u = (u + 0x7FFFu + ((u >> 16) & 1u)) >> 16;
  return (short)u;
}

// ---------------------------------------------------------------------------
// 1. prep: (a) swizzle aw [K=1024][N=1024] into MFMA B-frags (awf),
//    (b) gather ht [k][b] from hid, (c) build fx/fh B-frags (N=64) straight
//    from emb/hid (j-stride contiguous -> coalesced 32B reads).
//    Frag layouts: N=64:  idx = ((kt*4  + ct)*64 + lane)*8 + j
//                  N=1024: idx = ((kt*64 + nt)*64 + lane)*8 + j
//    element = src[kt*32 + (lane>>4)*8 + j][tile*16 + (lane&15)]
// ---------------------------------------------------------------------------
__global__ __launch_bounds__(256) void k_prep(const int* __restrict__ idx,
    const float* __restrict__ emb, const float* __restrict__ hid,
    const float* __restrict__ aw, float* __restrict__ ht,
    short* __restrict__ fx, short* __restrict__ fh, short* __restrict__ awf) {
  int t = blockIdx.x * 256 + threadIdx.x;   // 131072 threads
  { // awf
    int lane = t & 63, nt = (t >> 6) & 63, kt = t >> 12;   // kt 0..31
    int kr = kt * 32 + ((lane >> 4) & 3) * 8;
    int col = nt * 16 + (lane & 15);
    const float* sp = aw + (size_t)kr * HS + col;
    s8v v;
#pragma unroll
    for (int j = 0; j < 8; j++) v[j] = bf16c(sp[(size_t)j * HS]);
    *(s8v*)(awf + (size_t)t * 8) = v;
  }
  if (t < 65536) { // ht gather (coalesced hid row reads)
    int b = t >> 10, k = t & 1023;
    ht[k * BS + b] = hid[(size_t)b * HS + k];
  }
  if (t < 8192) { // fx from emb via idx
    int lane = t & 63, ct = (t >> 6) & 3, kt = t >> 8;
    int col = ct * 16 + (lane & 15);
    int kr = kt * 32 + ((lane >> 4) & 3) * 8;
    const float* sp = emb + (size_t)idx[col] * HS + kr;
    s8v v;
#pragma unroll
    for (int j = 0; j < 8; j++) v[j] = bf16c(sp[j]);
    *(s8v*)(fx + (size_t)t * 8) = v;
  } else if (t < 16384) { // fh from hid
    int t2 = t - 8192;
    int lane = t2 & 63, ct = (t2 >> 6) & 3, kt = t2 >> 8;
    int col = ct * 16 + (lane & 15);
    int kr = kt * 32 + ((lane >> 4) & 3) * 8;
    const float* sp = hid + (size_t)col * HS + kr;
    s8v v;
#pragma unroll
    for (int j = 0; j < 8; j++) v[j] = bf16c(sp[j]);
    *(s8v*)(fh + (size_t)t2 * 8) = v;
  }
}

// ---------------------------------------------------------------------------
// 2. Split-K MFMA GEMM: dst[M][64] = W[M][K]@X. Block = one 16-row m-tile;
//    4 waves each own K/4; LDS combine. OL 0: fp32 dst[row*64+col] (gates).
//    OL 1: tanh -> bf16 dst[col*HS+row] (concat -> cbf).
// ---------------------------------------------------------------------------
template<int K, int OL>
__global__ __launch_bounds__(256) void mfsk(
    const float* __restrict__ W0, const short* __restrict__ xf0,
    const float* __restrict__ bias0, void* __restrict__ dst0,
    const float* __restrict__ W1, const short* __restrict__ xf1,
    const float* __restrict__ bias1, void* __restrict__ dst1) {
  const float* W    = blockIdx.y ? W1 : W0;
  const short* xf   = blockIdx.y ? xf1 : xf0;
  const float* bias = blockIdx.y ? bias1 : bias0;
  void* dst         = blockIdx.y ? dst1 : dst0;
  int lane = threadIdx.x & 63;
  int ks = threadIdx.x >> 6;           // k-slice 0..3
  int mt = blockIdx.x;                 // 16-row tile
  int row = mt * 16 + (lane & 15);
  const int KW = (K / 32) / 4;         // k-tiles per wave
  const float* wp = W + (size_t)row * K + ((lane >> 4) * 8);
  const s8v* xp = (const s8v*)xf + lane;
  f4v acc0 = {0,0,0,0}, acc1 = {0,0,0,0}, acc2 = {0,0,0,0}, acc3 = {0,0,0,0};
#pragma unroll 4
  for (int kk = 0; kk < KW; kk++) {
    int kt = ks * KW + kk;
    float4 wa = *(const float4*)(wp + (size_t)kt * 32);
    float4 wb = *(const float4*)(wp + (size_t)kt * 32 + 4);
    s8v a;
    a[0] = bf16c(wa.x); a[1] = bf16c(wa.y); a[2] = bf16c(wa.z); a[3] = bf16c(wa.w);
    a[4] = bf16c(wb.x); a[5] = bf16c(wb.y); a[6] = bf16c(wb.z); a[7] = bf16c(wb.w);
    const s8v* xk = xp + (size_t)kt * 256;
    acc0 = __builtin_amdgcn_mfma_f32_16x16x32_bf16(a, xk[0],   acc0, 0, 0, 0);
    acc1 = __builtin_amdgcn_mfma_f32_16x16x32_bf16(a, xk[64],  acc1, 0, 0, 0);
    acc2 = __builtin_amdgcn_mfma_f32_16x16x32_bf16(a, xk[128], acc2, 0, 0, 0);
    acc3 = __builtin_amdgcn_mfma_f32_16x16x32_bf16(a, xk[192], acc3, 0, 0, 0);
  }
  __shared__ float red[4][4][4][64];   // [ks][ct][r][lane] = 16 KB
#pragma unroll
  for (int r = 0; r < 4; r++) {
    red[ks][0][r][lane] = acc0[r];
    red[ks][1][r][lane] = acc1[r];
    red[ks][2][r][lane] = acc2[r];
    red[ks][3][r][lane] = acc3[r];
  }
  __syncthreads();
  int ct = ks;
  int rr0 = mt * 16 + (lane >> 4) * 4;
  int col = ct * 16 + (lane & 15);
#pragma unroll
  for (int r = 0; r < 4; r++) {
    float v = red[0][ct][r][lane] + red[1][ct][r][lane] +
              red[2][ct][r][lane] + red[3][ct][r][lane] + bias[rr0 + r];
    if (OL == 0)
      ((float*)dst)[(size_t)(rr0 + r) * BS + col] = v;
    else
      ((short*)dst)[(size_t)col * HS + rr0 + r] = bf16c(tanhf(v));
  }
}

// ---------------------------------------------------------------------------
// 3. GRU nonlinearity -> out_h [1,B,H] + fcat-low bf16 frags (k=i, col=b)
// ---------------------------------------------------------------------------
__global__ __launch_bounds__(256) void k_hnew(const float* __restrict__ gxt,
    const float* __restrict__ ght, const float* __restrict__ ht,
    float* __restrict__ out_h, short* __restrict__ fcat) {
  int tid = blockIdx.x * 256 + threadIdx.x;   // 65536
  int b = tid & 63, i = tid >> 6;
  float r = sigmf(gxt[i * BS + b] + ght[i * BS + b]);
  float z = sigmf(gxt[(HS + i) * BS + b] + ght[(HS + i) * BS + b]);
  float n = tanhf(gxt[(2 * HS + i) * BS + b] + r * ght[(2 * HS + i) * BS + b]);
  float hn = (1.0f - z) * n + z * ht[i * BS + b];
  out_h[(size_t)b * HS + i] = hn;
  int kt = i >> 5, j = i & 7;
  int lane = (b & 15) | (((i >> 3) & 3) << 4);
  int ct = b >> 4;
  fcat[((size_t)((kt * 4 + ct) * 64 + lane)) * 8 + j] = bf16c(hn);
}

// ---------------------------------------------------------------------------
// 4. q = h_new @ aw via MFMA. A = out_h [b][g] (row-major, contiguous),
//    B = awf frags. attn_b dropped (per-b constant -> cancels in softmax).
// ---------------------------------------------------------------------------
__global__ __launch_bounds__(256) void k_qgemm(const float* __restrict__ hnr,
    const short* __restrict__ awf, float* __restrict__ qrow) {
  int lane = threadIdx.x & 63;
  int mt = threadIdx.x >> 6;    // b-tile 0..3
  int nt = blockIdx.x;          // h-tile 0..63
  const float* ap = hnr + (size_t)(mt * 16 + (lane & 15)) * HS + ((lane >> 4) * 8);
  const s8v* bp = (const s8v*)awf + (size_t)nt * 64 + lane;
  f4v acc = {0,0,0,0};
#pragma unroll 4
  for (int kt = 0; kt < 32; kt++) {
    float4 wa = *(const float4*)(ap + kt * 32);
    float4 wb = *(const float4*)(ap + kt * 32 + 4);
    s8v a;
    a[0] = bf16c(wa.x); a[1] = bf16c(wa.y); a[2] = bf16c(wa.z); a[3] = bf16c(wa.w);
    a[4] = bf16c(wb.x); a[5] = bf16c(wb.y); a[6] = bf16c(wb.z); a[7] = bf16c(wb.w);
    acc = __builtin_amdgcn_mfma_f32_16x16x32_bf16(a, bp[(size_t)kt * 4096], acc, 0, 0, 0);
  }
  int r0 = mt * 16 + (lane >> 4) * 4;
  int hcol = nt * 16 + (lane & 15);
#pragma unroll
  for (int r = 0; r < 4; r++)
    qrow[(size_t)(r0 + r) * HS + hcol] = acc[r];
}

// ---------------------------------------------------------------------------
// 5. Fused scores + online softmax + context: ONE WAVE per (b, chunk).
//    Lean register footprint (~85 VGPR): 1 position/iter + 1-ahead prefetch;
//    launch_bounds(256,4) guarantees >=16 waves/CU to hide HBM latency.
// ---------------------------------------------------------------------------
__global__ __launch_bounds__(256, 4) void k_attn(const float* __restrict__ enc,
    const float* __restrict__ qrow, float* __restrict__ scores,
    float* __restrict__ mch, float* __restrict__ lch, float* __restrict__ ctxp) {
  int lane = threadIdx.x & 63;
  int w = blockIdx.x * 4 + (threadIdx.x >> 6);   // 4096 waves
  int b = w & 63;
  int ch = w >> 6;                               // 0..63
  const float* qb = qrow + (size_t)b * HS + lane * 4;
  float4 q0 = *(const float4*)(qb + 0);
  float4 q1 = *(const float4*)(qb + 256);
  float4 q2 = *(const float4*)(qb + 512);
  float4 q3 = *(const float4*)(qb + 768);
  int s0 = ch * SCH;
  const float* ep = enc + ((size_t)s0 * BS + b) * HS + lane * 4;
  float4 e0 = *(const float4*)(ep + 0);
  float4 e1 = *(const float4*)(ep + 256);
  float4 e2 = *(const float4*)(ep + 512);
  float4 e3 = *(const float4*)(ep + 768);
  float m = -1e30f, l = 0.f;
  float4 a0 = {0,0,0,0}, a1 = {0,0,0,0}, a2 = {0,0,0,0}, a3 = {0,0,0,0};
  for (int si = 0; si < SCH; si++) {
    float4 c0 = e0, c1 = e1, c2 = e2, c3 = e3;
    if (si + 1 < SCH) {
      const float* np = ep + (size_t)BS * HS;
      e0 = *(const float4*)(np + 0);
      e1 = *(const float4*)(np + 256);
      e2 = *(const float4*)(np + 512);
      e3 = *(const float4*)(np + 768);
    }
    ep += (size_t)BS * HS;
    float d0 = fmaf(c0.x,q0.x, fmaf(c0.y,q0.y, fmaf(c0.z,q0.z, c0.w*q0.w)));
    float d1 = fmaf(c1.x,q1.x, fmaf(c1.y,q1.y, fmaf(c1.z,q1.z, c1.w*q1.w)));
    float d2 = fmaf(c2.x,q2.x, fmaf(c2.y,q2.y, fmaf(c2.z,q2.z, c2.w*q2.w)));
    float d3 = fmaf(c3.x,q3.x, fmaf(c3.y,q3.y, fmaf(c3.z,q3.z, c3.w*q3.w)));
    float p = (d0 + d1) + (d2 + d3);
#pragma unroll
    for (int off = 32; off; off >>= 1) p += __shfl_xor(p, off, 64);
    if (lane == 0) scores[(size_t)b * SS + s0 + si] = p;
    float mn = fmaxf(m, p);
    float sc = __expf(m - mn);     // first iter: exp(-huge) = 0
    float pr = __expf(p - mn);
    l = fmaf(l, sc, pr);
    a0.x = fmaf(a0.x, sc, pr * c0.x); a0.y = fmaf(a0.y, sc, pr * c0.y);
    a0.z = fmaf(a0.z, sc, pr * c0.z); a0.w = fmaf(a0.w, sc, pr * c0.w);
    a1.x = fmaf(a1.x, sc, pr * c1.x); a1.y = fmaf(a1.y, sc, pr * c1.y);
    a1.z = fmaf(a1.z, sc, pr * c1.z); a1.w = fmaf(a1.w, sc, pr * c1.w);
    a2.x = fmaf(a2.x, sc, pr * c2.x); a2.y = fmaf(a2.y, sc, pr * c2.y);
    a2.z = fmaf(a2.z, sc, pr * c2.z); a2.w = fmaf(a2.w, sc, pr * c2.w);
    a3.x = fmaf(a3.x, sc, pr * c3.x); a3.y = fmaf(a3.y, sc, pr * c3.y);
    a3.z = fmaf(a3.z, sc, pr * c3.z); a3.w = fmaf(a3.w, sc, pr * c3.w);
    m = mn;
  }
  if (lane == 0) { mch[b * NCH + ch] = m; lch[b * NCH + ch] = l; }
  float* cp = ctxp + ((size_t)(b * NCH + ch)) * HS + lane * 4;
  *(float4*)(cp + 0)   = a0;
  *(float4*)(cp + 256) = a1;
  *(float4*)(cp + 512) = a2;
  *(float4*)(cp + 768) = a3;
}

// ---------------------------------------------------------------------------
// 6. Combine chunk partials -> fcat-high bf16 frags + softmax weights output
// ---------------------------------------------------------------------------
__global__ __launch_bounds__(256) void k_combine(const float* __restrict__ mch,
    const float* __restrict__ lch, const float* __restrict__ ctxp,
    const float* __restrict__ scores, short* __restrict__ fcat,
    float* __restrict__ wout) {
  int b = blockIdx.x;
  int t = threadIdx.x;
  __shared__ float sm[NCH], sl[NCH], ssc[NCH];
  if (t < NCH) { sm[t] = mch[b * NCH + t]; sl[t] = lch[b * NCH + t]; }
  __syncthreads();
  float mstar = -1e30f;
  for (int c = 0; c < NCH; c++) mstar = fmaxf(mstar, sm[c]);
  if (t < NCH) ssc[t] = __expf(sm[t] - mstar);
  __syncthreads();
  float L = 0.f;
  for (int c = 0; c < NCH; c++) L = fmaf(sl[c], ssc[c], L);
  float invL = 1.0f / L;
  int h = blockIdx.y * 256 + t;
  float acc = 0.f;
  for (int c = 0; c < NCH; c++)
    acc = fmaf(ctxp[((size_t)(b * NCH + c)) * HS + h], ssc[c], acc);
  float ctx = acc * invL;
  int kc = HS + h;
  int kt = kc >> 5, j = kc & 7;
  int lane2 = (b & 15) | (((kc >> 3) & 3) << 4);
  int ct = b >> 4;
  fcat[((size_t)((kt * 4 + ct) * 64 + lane2)) * 8 + j] = bf16c(ctx);
  if (blockIdx.y == 0)
    for (int s = t; s < SS; s += 256)
      wout[(size_t)b * SS + s] = __expf(scores[(size_t)b * SS + s] - mstar) * invL;
}

// ---------------------------------------------------------------------------
// 7. output = concat_output @ out_w^T + out_b. A = cbf [b][k] bf16 (direct
//    16B frag loads), B = ow rows converted in-register. D[b][v] coalesced.
// ---------------------------------------------------------------------------
__global__ __launch_bounds__(256) void k_out2(const short* __restrict__ cbf,
    const float* __restrict__ ow, const float* __restrict__ ob,
    float* __restrict__ out0) {
  int lane = threadIdx.x & 63;
  int wv = threadIdx.x >> 6;
  int nt = blockIdx.x * 4 + wv;   // 0..1999 v-tiles
  int v0 = nt * 16;
  const float* wp = ow + (size_t)(v0 + (lane & 15)) * HS + ((lane >> 4) * 8);
  const short* a0p = cbf + (size_t)(0  + (lane & 15)) * HS + ((lane >> 4) * 8);
  const short* a1p = a0p + (size_t)16 * HS;
  const short* a2p = a0p + (size_t)32 * HS;
  const short* a3p = a0p + (size_t)48 * HS;
  f4v acc0 = {0,0,0,0}, acc1 = {0,0,0,0}, acc2 = {0,0,0,0}, acc3 = {0,0,0,0};
#pragma unroll 4
  for (int kt = 0; kt < 32; kt++) {
    float4 wa = *(const float4*)(wp + kt * 32);
    float4 wb = *(const float4*)(wp + kt * 32 + 4);
    s8v bf;
    bf[0] = bf16c(wa.x); bf[1] = bf16c(wa.y); bf[2] = bf16c(wa.z); bf[3] = bf16c(wa.w);
    bf[4] = bf16c(wb.x); bf[5] = bf16c(wb.y); bf[6] = bf16c(wb.z); bf[7] = bf16c(wb.w);
    s8v fa0 = *(const s8v*)(a0p + kt * 32);
    s8v fa1 = *(const s8v*)(a1p + kt * 32);
    s8v fa2 = *(const s8v*)(a2p + kt * 32);
    s8v fa3 = *(const s8v*)(a3p + kt * 32);
    acc0 = __builtin_amdgcn_mfma_f32_16x16x32_bf16(fa0, bf, acc0, 0, 0, 0);
    acc1 = __builtin_amdgcn_mfma_f32_16x16x32_bf16(fa1, bf, acc1, 0, 0, 0);
    acc2 = __builtin_amdgcn_mfma_f32_16x16x32_bf16(fa2, bf, acc2, 0, 0, 0);
    acc3 = __builtin_amdgcn_mfma_f32_16x16x32_bf16(fa3, bf, acc3, 0, 0, 0);
  }
  float bv = ob[v0 + (lane & 15)];
  int rb = (lane >> 4) * 4;
  int vc = v0 + (lane & 15);
#pragma unroll
  for (int r = 0; r < 4; r++) {
    out0[(size_t)(0  + rb + r) * VS + vc] = acc0[r] + bv;
    out0[(size_t)(16 + rb + r) * VS + vc] = acc1[r] + bv;
    out0[(size_t)(32 + rb + r) * VS + vc] = acc2[r] + bv;
    out0[(size_t)(48 + rb + r) * VS + vc] = acc3[r] + bv;
  }
}

// ---------------------------------------------------------------------------
extern "C" void kernel_launch(void* const* d_in, const int* in_sizes, int n_in,
                              void* d_out, int out_size, void* d_ws, size_t ws_size,
                              hipStream_t stream) {
  const int*   idx  = (const int*)d_in[0];
  const float* hid  = (const float*)d_in[1];
  const float* enc  = (const float*)d_in[2];
  const float* emb  = (const float*)d_in[3];
  const float* w_ih = (const float*)d_in[4];
  const float* w_hh = (const float*)d_in[5];
  const float* b_ih = (const float*)d_in[6];
  const float* b_hh = (const float*)d_in[7];
  const float* aw   = (const float*)d_in[8];
  // d_in[9] = attn_b: per-b constant on every score -> cancels in softmax.
  const float* cw   = (const float*)d_in[10];
  const float* cb   = (const float*)d_in[11];
  const float* ow   = (const float*)d_in[12];
  const float* ob   = (const float*)d_in[13];

  float* out0  = (float*)d_out;                   // [B, V]
  float* out_h = out0 + (size_t)BS * VS;          // [1, B, H]
  float* out_w = out_h + (size_t)BS * HS;         // [B, 1, S]

  // workspace (~22 MB)
  float* ws   = (float*)d_ws;
  float* gxt  = ws;                               // [3H][B]
  float* ght  = gxt + (size_t)3 * HS * BS;        // [3H][B]
  float* ht   = ght + (size_t)3 * HS * BS;        // [H][B]
  float* qrow = ht  + (size_t)HS * BS;            // [B][H]
  float* scr  = qrow + (size_t)HS * BS;           // [B][S]
  float* mch  = scr + (size_t)BS * SS;            // [B][NCH]
  float* lch  = mch + (size_t)BS * NCH;           // [B][NCH]
  float* ctxp = lch + (size_t)BS * NCH;           // [B*NCH][H]  (16 MB)
  short* awf  = (short*)(ctxp + (size_t)BS * NCH * HS);  // 1M shorts
  short* fx   = awf + (size_t)HS * HS;            // 64K shorts
  short* fh   = fx  + (size_t)HS * BS;            // 64K shorts
  short* fcat = fh  + (size_t)HS * BS;            // 128K shorts
  short* cbf  = fcat + (size_t)2 * HS * BS;       // 64K shorts

  k_prep   <<<dim3(512), dim3(256), 0, stream>>>(idx, emb, hid, aw, ht, fx, fh, awf);
  mfsk<HS, 0><<<dim3(3 * HS / 16, 2), dim3(256), 0, stream>>>(
      w_ih, fx, b_ih, gxt, w_hh, fh, b_hh, ght);
  k_hnew   <<<dim3(HS * BS / 256), dim3(256), 0, stream>>>(gxt, ght, ht, out_h, fcat);
  k_qgemm  <<<dim3(HS / 16), dim3(256), 0, stream>>>(out_h, awf, qrow);
  k_attn   <<<dim3(BS * NCH / 4), dim3(256), 0, stream>>>(enc, qrow, scr, mch, lch, ctxp);
  k_combine<<<dim3(BS, 4), dim3(256), 0, stream>>>(mch, lch, ctxp, scr, fcat, out_w);
  mfsk<2 * HS, 1><<<dim3(HS / 16, 1), dim3(256), 0, stream>>>(
      cw, fcat, cb, cbf, cw, fcat, cb, cbf);
  k_out2   <<<dim3(VS / 64), dim3(256), 0, stream>>>(cbf, ow, ob, out0);
}